// Round 5
// baseline (216.142 us; speedup 1.0000x reference)
//
#include <hip/hip_runtime.h>
#include <math.h>

// ---------------------------------------------------------------------------
// HMHA round 5 (isolation round): round-3 components + ONLY statsup fusion.
//   - cvt2_k / pool_k: separate launches (round-3 proven).
//   - mgemm_k: single-buffered, global_load_lds(16B) + XOR swizzle (round-3).
//   - attn_k: fused norm+QK^T+online softmax+PV (round-3 proven).
//   - statsup_k: analytic BN stats + bilinear upsample + BN affine in ONE
//     kernel per channel (lowT read once; proven correct in round 4).
// ---------------------------------------------------------------------------

typedef unsigned short u16;
typedef u16 u16x8 __attribute__((ext_vector_type(8)));
typedef u16 u16x4 __attribute__((ext_vector_type(4)));
typedef short s16x8 __attribute__((ext_vector_type(8)));
typedef float f32x4 __attribute__((ext_vector_type(4)));

__device__ __forceinline__ float b2f(u16 u) {
  union { unsigned u; float f; } v;
  v.u = (unsigned)u << 16;
  return v.f;
}
__device__ __forceinline__ u16 f2b(float f) {
  union { float f; unsigned u; } v;
  v.f = f;
  unsigned r = (v.u + 0x7fffu + ((v.u >> 16) & 1u)) >> 16;
  return (u16)r;
}
__device__ __forceinline__ f32x4 mfma_bf16(s16x8 a, s16x8 b, f32x4 c) {
  return __builtin_amdgcn_mfma_f32_16x16x32_bf16(a, b, c, 0, 0, 0);
}
// global -> LDS direct 16B load (dest = wave-uniform base + lane*16)
__device__ __forceinline__ void gload16(const u16* g, u16* l) {
  unsigned loff = (unsigned)(unsigned long long)l;
  __builtin_amdgcn_global_load_lds(
      (const __attribute__((address_space(1))) void*)g,
      (__attribute__((address_space(3))) void*)loff, 16, 0, 0);
}

// ---------------- both weight conversions, one launch -----------------------
__global__ __launch_bounds__(256) void cvt2_k(const float* __restrict__ a,
                                              u16* __restrict__ da, int n4a,
                                              const float* __restrict__ b,
                                              u16* __restrict__ db, int n4b) {
  int idx = blockIdx.x * 256 + threadIdx.x;
  const float* s;
  u16* d;
  if (idx < n4a) {
    s = a; d = da;
  } else {
    idx -= n4a;
    if (idx >= n4b) return;
    s = b; d = db;
  }
  float4 v = ((const float4*)s)[idx];
  u16x4 o;
  o.x = f2b(v.x); o.y = f2b(v.y); o.z = f2b(v.z); o.w = f2b(v.w);
  ((u16x4*)d)[idx] = o;
}

// ---------------- pool 4x4 mean -> xrN bf16 [b*256+pix][1024] ---------------
__global__ __launch_bounds__(256) void pool_k(const float* __restrict__ x,
                                              u16* __restrict__ xrN) {
  int bid = blockIdx.x;
  int g = bid >> 3, xcd = bid & 7;
  int c = xcd * 128 + (g & 127);
  int b = g >> 7;
  int t = threadIdx.x;
  int i = t >> 4, j = t & 15;
  const float* p = x + ((long)(b * 1024 + c)) * 4096 + (long)i * 256 + j * 4;
  float s = 0.f;
#pragma unroll
  for (int r = 0; r < 4; ++r) {
    float4 v = *(const float4*)(p + r * 64);
    s += v.x + v.y + v.z + v.w;
  }
  xrN[((long)(b << 8) + t) * 1024 + c] = f2b(s * 0.0625f);
}

// ---------------- MFMA GEMM, single-buffer, gload_lds + XOR swizzle ---------
// C[M][N] = A[M][K] * B[N][K]^T. 128x128 tile, BK=64, 4 waves of 64x64.
// LDS chunk(16B) swizzle: phys = logical ^ (row&7), same involution on the
// global source chunk and the ds_read chunk (rule: both-sides-or-neither).
template <bool OUT_BF16>
__global__ __launch_bounds__(256) void mgemm_k(const u16* __restrict__ A,
                                               const u16* __restrict__ B,
                                               void* __restrict__ C, int K,
                                               int lda, int ldb, int ldc) {
  constexpr int BM = 128, BN = 128, BK = 64;
  __shared__ u16 As[BM * BK];
  __shared__ u16 Bs[BN * BK];
  const int t = threadIdx.x;
  const int lane = t & 63, wave = t >> 6;
  const int l15 = lane & 15, l4 = lane >> 4;
  const int row0 = blockIdx.y * BM, col0 = blockIdx.x * BN;
  const int wr = (wave >> 1) * 64, wc = (wave & 1) * 64;
  const int srow = t >> 3;               // staging row for this thread
  const int sch = (t & 7) ^ (srow & 7);  // swizzled source chunk
  f32x4 acc[4][4] = {};

  for (int k0 = 0; k0 < K; k0 += BK) {
    __syncthreads();
#pragma unroll
    for (int p = 0; p < 4; ++p) {   // 4 passes x 256 thr x 16B = 16 KB
      gload16(&A[(long)(row0 + p * 32 + srow) * lda + k0 + sch * 8],
              &As[(p * 256 + wave * 64) * 8]);
      gload16(&B[(long)(col0 + p * 32 + srow) * ldb + k0 + sch * 8],
              &Bs[(p * 256 + wave * 64) * 8]);
    }
    __syncthreads();
#pragma unroll
    for (int kk = 0; kk < BK / 32; ++kk) {
      s16x8 a[4], bfr[4];
#pragma unroll
      for (int i = 0; i < 4; i++) {
        int r = wr + i * 16 + l15;
        int ph = (kk * 4 + l4) ^ (r & 7);
        a[i] = *(const s16x8*)&As[r * 64 + ph * 8];
      }
#pragma unroll
      for (int j = 0; j < 4; j++) {
        int r = wc + j * 16 + l15;
        int ph = (kk * 4 + l4) ^ (r & 7);
        bfr[j] = *(const s16x8*)&Bs[r * 64 + ph * 8];
      }
#pragma unroll
      for (int i = 0; i < 4; i++)
#pragma unroll
        for (int j = 0; j < 4; j++)
          acc[i][j] = mfma_bf16(a[i], bfr[j], acc[i][j]);
    }
  }
#pragma unroll
  for (int i = 0; i < 4; i++)
#pragma unroll
    for (int j = 0; j < 4; j++)
#pragma unroll
      for (int q = 0; q < 4; q++) {
        long r = row0 + wr + i * 16 + l4 * 4 + q;
        long c = col0 + wc + j * 16 + l15;
        if constexpr (OUT_BF16)
          ((u16*)C)[r * ldc + c] = f2b(acc[i][j][q]);
        else
          ((float*)C)[r * ldc + c] = acc[i][j][q];
      }
}

// ---------------- fused attention: norm + QK^T + softmax + PV ---------------
__global__ __launch_bounds__(256) void attn_k(const u16* __restrict__ qkv,
                                              const float* __restrict__ temp,
                                              u16* __restrict__ attN) {
  int blk = blockIdx.x;
  int bh = blk >> 1, half = blk & 1;
  int b = bh >> 3, h = bh & 7;
  __shared__ u16 qs[128][40];
  __shared__ u16 ks[256][40];
  __shared__ u16 vs[32][264];
  __shared__ u16 Ps[4][32][40];
  int t = threadIdx.x, lane = t & 63, wave = t >> 6;
  int l15 = lane & 15, l4 = lane >> 4;
  long base = (long)b * 256;

  {
    const u16* V = qkv + (long)(512 + h * 32) * 4096 + base;
#pragma unroll
    for (int p = 0; p < 4; ++p) {
      int c = p * 256 + t;
      int row = c >> 5, off = (c & 31) * 8;
      *(u16x8*)&vs[row][off] = *(const u16x8*)&V[(long)row * 4096 + off];
    }
  }
  {
    const u16* Kp = qkv + (long)(256 + h * 32) * 4096 + base + t;
    float v[32], ss = 0.f;
#pragma unroll
    for (int d = 0; d < 32; ++d) {
      v[d] = b2f(Kp[(long)d * 4096]);
      ss += v[d] * v[d];
    }
    float sc = 1.f / fmaxf(sqrtf(ss), 1e-12f);
#pragma unroll
    for (int d = 0; d < 32; ++d) ks[t][d] = f2b(v[d] * sc);
  }
  if (t < 128) {
    const u16* Qp = qkv + (long)(h * 32) * 4096 + base + half * 128 + t;
    float v[32], ss = 0.f;
#pragma unroll
    for (int d = 0; d < 32; ++d) {
      v[d] = b2f(Qp[(long)d * 4096]);
      ss += v[d] * v[d];
    }
    float sc = temp[h] / fmaxf(sqrtf(ss), 1e-12f);
#pragma unroll
    for (int d = 0; d < 32; ++d) qs[t][d] = f2b(v[d] * sc);
  }
  __syncthreads();

  int r0 = wave * 32;
  s16x8 aq[2];
#pragma unroll
  for (int i = 0; i < 2; ++i)
    aq[i] = *(const s16x8*)&qs[r0 + i * 16 + l15][l4 * 8];
  f32x4 O[2][2] = {};
  float mrow[2][4], lrow[2][4];
#pragma unroll
  for (int i = 0; i < 2; ++i)
#pragma unroll
    for (int q = 0; q < 4; ++q) {
      mrow[i][q] = -1e30f;
      lrow[i][q] = 0.f;
    }

  for (int m0 = 0; m0 < 256; m0 += 32) {
    f32x4 s[2][2] = {};
    s16x8 bk_[2];
#pragma unroll
    for (int j = 0; j < 2; ++j)
      bk_[j] = *(const s16x8*)&ks[m0 + j * 16 + l15][l4 * 8];
#pragma unroll
    for (int i = 0; i < 2; ++i)
#pragma unroll
      for (int j = 0; j < 2; ++j)
        s[i][j] = mfma_bf16(aq[i], bk_[j], s[i][j]);
#pragma unroll
    for (int i = 0; i < 2; ++i) {
      float cm[4];
#pragma unroll
      for (int q = 0; q < 4; ++q) cm[q] = fmaxf(s[i][0][q], s[i][1][q]);
#pragma unroll
      for (int sh = 1; sh < 16; sh <<= 1)
#pragma unroll
        for (int q = 0; q < 4; ++q) cm[q] = fmaxf(cm[q], __shfl_xor(cm[q], sh));
      float al[4], ps[4];
#pragma unroll
      for (int q = 0; q < 4; ++q) {
        float mn = fmaxf(mrow[i][q], cm[q]);
        al[q] = __expf(mrow[i][q] - mn);
        mrow[i][q] = mn;
        float p0 = __expf(s[i][0][q] - mn);
        float p1 = __expf(s[i][1][q] - mn);
        s[i][0][q] = p0;
        s[i][1][q] = p1;
        ps[q] = p0 + p1;
      }
#pragma unroll
      for (int sh = 1; sh < 16; sh <<= 1)
#pragma unroll
        for (int q = 0; q < 4; ++q) ps[q] += __shfl_xor(ps[q], sh);
#pragma unroll
      for (int q = 0; q < 4; ++q) lrow[i][q] = lrow[i][q] * al[q] + ps[q];
#pragma unroll
      for (int jd = 0; jd < 2; ++jd)
#pragma unroll
        for (int q = 0; q < 4; ++q) O[i][jd][q] *= al[q];
#pragma unroll
      for (int j = 0; j < 2; ++j)
#pragma unroll
        for (int q = 0; q < 4; ++q)
          Ps[wave][i * 16 + l4 * 4 + q][j * 16 + l15] = f2b(s[i][j][q]);
    }
    s16x8 pa[2], bv[2];
#pragma unroll
    for (int i = 0; i < 2; ++i)
      pa[i] = *(const s16x8*)&Ps[wave][i * 16 + l15][l4 * 8];
#pragma unroll
    for (int jd = 0; jd < 2; ++jd)
      bv[jd] = *(const s16x8*)&vs[jd * 16 + l15][m0 + l4 * 8];
#pragma unroll
    for (int i = 0; i < 2; ++i)
#pragma unroll
      for (int jd = 0; jd < 2; ++jd)
        O[i][jd] = mfma_bf16(pa[i], bv[jd], O[i][jd]);
  }
  long rbase = base + half * 128 + r0;
#pragma unroll
  for (int i = 0; i < 2; ++i)
#pragma unroll
    for (int jd = 0; jd < 2; ++jd)
#pragma unroll
      for (int q = 0; q < 4; ++q)
        attN[(rbase + i * 16 + l4 * 4 + q) * 256 + h * 32 + jd * 16 + l15] =
            f2b(O[i][jd][q] / lrow[i][q]);
}

// ---------------- fused: analytic BN stats + upsample + BN affine -----------
// grid 1024 = one block per channel o. Phase 1: stats over all 16 batches
// (lowT row cached in LDS). Phase 2: bilinear 4x upsample + affine writes.
__global__ __launch_bounds__(256) void statsup_k(const float* __restrict__ low,
                                                 const float* __restrict__ gamma,
                                                 const float* __restrict__ beta,
                                                 float* __restrict__ out) {
  int o = blockIdx.x, t = threadIdx.x;
  __shared__ float Lall[16][256];   // all batches' low-res rows (16 KB)
  __shared__ float cw[16];
  __shared__ float A3[16][3];
  __shared__ float r1[4], r2[4];
  __shared__ float kab[2];

  // load lowT[o][...] (16 KB contiguous) as float4
#pragma unroll
  for (int q = 0; q < 4; ++q) {
    float4 v = ((const float4*)(low + (long)o * 4096))[q * 256 + t];
    int b = q * 4 + (t >> 6), pix = (t & 63) * 4;
    *(float4*)&Lall[b][pix] = v;
  }
  if (t < 16) {
    cw[t] = 0.f;
    A3[t][0] = A3[t][1] = A3[t][2] = 0.f;
  }
  __syncthreads();
  if (t < 64) {
    float src = 0.25f * t - 0.375f;
    float fl = floorf(src);
    float f = src - fl;
    int i0 = (int)fl, i1 = i0 + 1;
    i0 = max(0, min(15, i0));
    i1 = max(0, min(15, i1));
    float w0 = 1.f - f, w1 = f;
    atomicAdd(&cw[i0], w0);
    atomicAdd(&cw[i1], w1);
    if (i0 == i1)
      atomicAdd(&A3[i0][1], 1.f);
    else {
      atomicAdd(&A3[i0][1], w0 * w0);
      atomicAdd(&A3[i1][1], w1 * w1);
      atomicAdd(&A3[i0][2], w0 * w1);
      atomicAdd(&A3[i1][0], w0 * w1);
    }
  }
  __syncthreads();
  int i = t >> 4, j = t & 15;
  float s1 = 0.f, s2 = 0.f;
#pragma unroll 4
  for (int b = 0; b < 16; ++b) {
    float Lc = Lall[b][t];
    s1 += cw[i] * cw[j] * Lc;
    float a2 = 0.f;
#pragma unroll
    for (int di = -1; di <= 1; ++di) {
      int ii = max(0, min(15, i + di));
      float ay = A3[i][di + 1];
#pragma unroll
      for (int dj = -1; dj <= 1; ++dj) {
        int jj = max(0, min(15, j + dj));
        a2 += ay * A3[j][dj + 1] * Lall[b][ii * 16 + jj];
      }
    }
    s2 += a2 * Lc;
  }
  int lane = t & 63, wid = t >> 6;
  for (int off = 32; off; off >>= 1) {
    s1 += __shfl_down(s1, off);
    s2 += __shfl_down(s2, off);
  }
  if (lane == 0) {
    r1[wid] = s1;
    r2[wid] = s2;
  }
  __syncthreads();
  if (t == 0) {
    s1 = r1[0] + r1[1] + r1[2] + r1[3];
    s2 = r2[0] + r2[1] + r2[2] + r2[3];
    float mean = s1 * (1.f / 65536.f);
    float var = s2 * (1.f / 65536.f) - mean * mean;
    float is = rsqrtf(var + 1e-5f);
    float g = gamma[o];
    kab[0] = g * is;
    kab[1] = beta[o] - mean * g * is;
  }
  __syncthreads();
  float ka = kab[0], kb = kab[1];

  // hoisted interpolation params: x depends on (t&15, jj), y on (it, t>>4)
  float fxv[4];
  int x0v[4], x1v[4];
  int xbase = (t & 15) * 4;
#pragma unroll
  for (int jj = 0; jj < 4; ++jj) {
    float sx = 0.25f * (xbase + jj) - 0.375f;
    float fl = floorf(sx);
    fxv[jj] = sx - fl;
    int xi = (int)fl;
    x0v[jj] = max(0, min(15, xi));
    x1v[jj] = max(0, min(15, xi + 1));
  }
  float fyv[4];
  int y0v[4], y1v[4];
  int ybase = t >> 4;
#pragma unroll
  for (int it = 0; it < 4; ++it) {
    float sy = 0.25f * (it * 16 + ybase) - 0.375f;
    float fl = floorf(sy);
    fyv[it] = sy - fl;
    int yi = (int)fl;
    y0v[it] = max(0, min(15, yi));
    y1v[it] = max(0, min(15, yi + 1));
  }

  for (int b = 0; b < 16; ++b) {
    float* op = out + ((long)b * 1024 + o) * 4096;
    const float* Ls = Lall[b];
#pragma unroll
    for (int it = 0; it < 4; ++it) {
      const float* R0 = &Ls[y0v[it] * 16];
      const float* R1 = &Ls[y1v[it] * 16];
      float fy = fyv[it];
      float vv[4];
#pragma unroll
      for (int jj = 0; jj < 4; ++jj) {
        float v0 = R0[x0v[jj]] + fxv[jj] * (R0[x1v[jj]] - R0[x0v[jj]]);
        float v1 = R1[x0v[jj]] + fxv[jj] * (R1[x1v[jj]] - R1[x0v[jj]]);
        vv[jj] = ka * (v0 + fy * (v1 - v0)) + kb;
      }
      float4 r;
      r.x = vv[0]; r.y = vv[1]; r.z = vv[2]; r.w = vv[3];
      *(float4*)(op + it * 1024 + t * 4) = r;
    }
  }
}

// ---------------------------------------------------------------------------
extern "C" void kernel_launch(void* const* d_in, const int* in_sizes, int n_in,
                              void* d_out, int out_size, void* d_ws,
                              size_t ws_size, hipStream_t stream) {
  const float* x = (const float*)d_in[0];
  const float* w_qkv = (const float*)d_in[1];
  const float* temp = (const float*)d_in[2];
  const float* w_proj = (const float*)d_in[3];
  const float* gamma = (const float*)d_in[4];
  const float* beta = (const float*)d_in[5];
  float* out = (float*)d_out;
  char* w = (char*)d_ws;

  u16* wqkv_b = (u16*)(w);                 // 1.50 MB
  u16* wproj_b = (u16*)(w + 1572864);      // 0.50 MB
  u16* xrN = (u16*)(w + 2097152);          // 8.0 MB  [4096][1024]
  u16* qkvb = (u16*)(w + 10485760);        // 6.0 MB  [768][4096]
  u16* attN = (u16*)(w + 16777216);        // 2.0 MB  [4096][256]
  float* lowT = (float*)(w + 18874368);    // 16 MB   [1024][4096]

  // 1) weights -> bf16 (one launch)
  cvt2_k<<<1024, 256, 0, stream>>>(w_qkv, wqkv_b, 196608, w_proj, wproj_b,
                                   65536);
  // 2) pool -> xrN
  pool_k<<<16384, 256, 0, stream>>>(x, xrN);
  // 3) qkv GEMM: M=768,N=4096,K=1024
  mgemm_k<true><<<dim3(32, 6), 256, 0, stream>>>(wqkv_b, xrN, qkvb, 1024, 1024,
                                                 1024, 4096);
  // 4) fused attention -> attN
  attn_k<<<256, 256, 0, stream>>>(qkvb, temp, attN);
  // 5) proj GEMM at low res: M=1024,N=4096,K=256
  mgemm_k<false><<<dim3(32, 8), 256, 0, stream>>>(wproj_b, attN, lowT, 256, 256,
                                                  256, 4096);
  // 6) fused stats + upsample + BN -> out
  statsup_k<<<1024, 256, 0, stream>>>(lowT, gamma, beta, out);
}

// Round 6
// 174.245 us; speedup vs baseline: 1.2404x; 1.2404x over previous
//
#include <hip/hip_runtime.h>
#include <math.h>

// ---------------------------------------------------------------------------
// HMHA round 6 (recombination of measured winners):
//   - cvtpool_k: weight cvt + pool in one launch         (R4, helped)
//   - mgemm_k: double-buffered LDS, gload_lds + XOR swz  (R4, helped ~12us)
//   - attn_k: fused norm+QK^T+softmax+PV                 (unchanged)
//   - stats_k + up_bn_k SEPARATE                         (R3; statsup fusion
//     regressed +30us: 1024-block write phase is latency-bound at 4 blk/CU)
// ---------------------------------------------------------------------------

typedef unsigned short u16;
typedef u16 u16x8 __attribute__((ext_vector_type(8)));
typedef u16 u16x4 __attribute__((ext_vector_type(4)));
typedef short s16x8 __attribute__((ext_vector_type(8)));
typedef float f32x4 __attribute__((ext_vector_type(4)));

__device__ __forceinline__ float b2f(u16 u) {
  union { unsigned u; float f; } v;
  v.u = (unsigned)u << 16;
  return v.f;
}
__device__ __forceinline__ u16 f2b(float f) {
  union { float f; unsigned u; } v;
  v.f = f;
  unsigned r = (v.u + 0x7fffu + ((v.u >> 16) & 1u)) >> 16;
  return (u16)r;
}
__device__ __forceinline__ f32x4 mfma_bf16(s16x8 a, s16x8 b, f32x4 c) {
  return __builtin_amdgcn_mfma_f32_16x16x32_bf16(a, b, c, 0, 0, 0);
}
// global -> LDS direct 16B load (dest = wave-uniform base + lane*16)
__device__ __forceinline__ void gload16(const u16* g, u16* l) {
  unsigned loff = (unsigned)(unsigned long long)l;
  __builtin_amdgcn_global_load_lds(
      (const __attribute__((address_space(1))) void*)g,
      (__attribute__((address_space(3))) void*)loff, 16, 0, 0);
}

// ---------------- fused: weight cvt (blocks 0..1023) + pool (rest) ----------
__global__ __launch_bounds__(256) void cvtpool_k(
    const float* __restrict__ wa, u16* __restrict__ da, int n4a,
    const float* __restrict__ wb, u16* __restrict__ db, int n4b,
    const float* __restrict__ x, u16* __restrict__ xrN) {
  int bid = blockIdx.x;
  if (bid < 1024) {
    int idx = bid * 256 + threadIdx.x;
    const float* s;
    u16* d;
    if (idx < n4a) {
      s = wa; d = da;
    } else {
      idx -= n4a;
      if (idx >= n4b) return;
      s = wb; d = db;
    }
    float4 v = ((const float4*)s)[idx];
    u16x4 o;
    o.x = f2b(v.x); o.y = f2b(v.y); o.z = f2b(v.z); o.w = f2b(v.w);
    ((u16x4*)d)[idx] = o;
    return;
  }
  bid -= 1024;
  int g = bid >> 3, xcd = bid & 7;
  int c = xcd * 128 + (g & 127);
  int b = g >> 7;
  int t = threadIdx.x;
  int i = t >> 4, j = t & 15;
  const float* p = x + ((long)(b * 1024 + c)) * 4096 + (long)i * 256 + j * 4;
  float s = 0.f;
#pragma unroll
  for (int r = 0; r < 4; ++r) {
    float4 v = *(const float4*)(p + r * 64);
    s += v.x + v.y + v.z + v.w;
  }
  xrN[((long)(b << 8) + t) * 1024 + c] = f2b(s * 0.0625f);
}

// ---------------- MFMA GEMM, double-buffered, gload_lds + XOR swizzle -------
// C[M][N] = A[M][K] * B[N][K]^T. 128x128 tile, BK=64, 4 waves of 64x64.
// LDS chunk(16B) swizzle: phys = logical ^ (row&7), same involution applied
// on the global source chunk and the ds_read chunk (rule: both-sides).
template <bool OUT_BF16>
__global__ __launch_bounds__(256) void mgemm_k(const u16* __restrict__ A,
                                               const u16* __restrict__ B,
                                               void* __restrict__ C, int K,
                                               int lda, int ldb, int ldc) {
  constexpr int BM = 128, BN = 128, BK = 64;
  __shared__ u16 As[2][BM * BK];
  __shared__ u16 Bs[2][BN * BK];
  const int t = threadIdx.x;
  const int lane = t & 63, wave = t >> 6;
  const int l15 = lane & 15, l4 = lane >> 4;
  const int row0 = blockIdx.y * BM, col0 = blockIdx.x * BN;
  const int wr = (wave >> 1) * 64, wc = (wave & 1) * 64;
  const int srow = t >> 3;               // staging row for this thread
  const int sch = (t & 7) ^ (srow & 7);  // swizzled source chunk
  f32x4 acc[4][4] = {};

  auto STG = [&](int buf, int k0) {
#pragma unroll
    for (int p = 0; p < 4; ++p) {
      gload16(&A[(long)(row0 + p * 32 + srow) * lda + k0 + sch * 8],
              &As[buf][(p * 256 + wave * 64) * 8]);
      gload16(&B[(long)(col0 + p * 32 + srow) * ldb + k0 + sch * 8],
              &Bs[buf][(p * 256 + wave * 64) * 8]);
    }
  };
  auto COMP = [&](int buf) {
#pragma unroll
    for (int kk = 0; kk < BK / 32; ++kk) {
      s16x8 a[4], bfr[4];
#pragma unroll
      for (int i = 0; i < 4; i++) {
        int r = wr + i * 16 + l15;
        int ph = (kk * 4 + l4) ^ (r & 7);
        a[i] = *(const s16x8*)&As[buf][r * 64 + ph * 8];
      }
#pragma unroll
      for (int j = 0; j < 4; j++) {
        int r = wc + j * 16 + l15;
        int ph = (kk * 4 + l4) ^ (r & 7);
        bfr[j] = *(const s16x8*)&Bs[buf][r * 64 + ph * 8];
      }
#pragma unroll
      for (int i = 0; i < 4; i++)
#pragma unroll
        for (int j = 0; j < 4; j++)
          acc[i][j] = mfma_bf16(a[i], bfr[j], acc[i][j]);
    }
  };

  STG(0, 0);
  __syncthreads();          // drains vmcnt(0): buf0 ready
  int cur = 0;
  for (int k0 = BK; k0 < K; k0 += BK) {
    STG(cur ^ 1, k0);       // issue next tile while computing current
    COMP(cur);
    __syncthreads();        // one barrier per iter (drains staging)
    cur ^= 1;
  }
  COMP(cur);

#pragma unroll
  for (int i = 0; i < 4; i++)
#pragma unroll
    for (int j = 0; j < 4; j++)
#pragma unroll
      for (int q = 0; q < 4; q++) {
        long r = row0 + wr + i * 16 + l4 * 4 + q;
        long c = col0 + wc + j * 16 + l15;
        if constexpr (OUT_BF16)
          ((u16*)C)[r * ldc + c] = f2b(acc[i][j][q]);
        else
          ((float*)C)[r * ldc + c] = acc[i][j][q];
      }
}

// ---------------- fused attention: norm + QK^T + softmax + PV ---------------
__global__ __launch_bounds__(256) void attn_k(const u16* __restrict__ qkv,
                                              const float* __restrict__ temp,
                                              u16* __restrict__ attN) {
  int blk = blockIdx.x;
  int bh = blk >> 1, half = blk & 1;
  int b = bh >> 3, h = bh & 7;
  __shared__ u16 qs[128][40];
  __shared__ u16 ks[256][40];
  __shared__ u16 vs[32][264];
  __shared__ u16 Ps[4][32][40];
  int t = threadIdx.x, lane = t & 63, wave = t >> 6;
  int l15 = lane & 15, l4 = lane >> 4;
  long base = (long)b * 256;

  {
    const u16* V = qkv + (long)(512 + h * 32) * 4096 + base;
#pragma unroll
    for (int p = 0; p < 4; ++p) {
      int c = p * 256 + t;
      int row = c >> 5, off = (c & 31) * 8;
      *(u16x8*)&vs[row][off] = *(const u16x8*)&V[(long)row * 4096 + off];
    }
  }
  {
    const u16* Kp = qkv + (long)(256 + h * 32) * 4096 + base + t;
    float v[32], ss = 0.f;
#pragma unroll
    for (int d = 0; d < 32; ++d) {
      v[d] = b2f(Kp[(long)d * 4096]);
      ss += v[d] * v[d];
    }
    float sc = 1.f / fmaxf(sqrtf(ss), 1e-12f);
#pragma unroll
    for (int d = 0; d < 32; ++d) ks[t][d] = f2b(v[d] * sc);
  }
  if (t < 128) {
    const u16* Qp = qkv + (long)(h * 32) * 4096 + base + half * 128 + t;
    float v[32], ss = 0.f;
#pragma unroll
    for (int d = 0; d < 32; ++d) {
      v[d] = b2f(Qp[(long)d * 4096]);
      ss += v[d] * v[d];
    }
    float sc = temp[h] / fmaxf(sqrtf(ss), 1e-12f);
#pragma unroll
    for (int d = 0; d < 32; ++d) qs[t][d] = f2b(v[d] * sc);
  }
  __syncthreads();

  int r0 = wave * 32;
  s16x8 aq[2];
#pragma unroll
  for (int i = 0; i < 2; ++i)
    aq[i] = *(const s16x8*)&qs[r0 + i * 16 + l15][l4 * 8];
  f32x4 O[2][2] = {};
  float mrow[2][4], lrow[2][4];
#pragma unroll
  for (int i = 0; i < 2; ++i)
#pragma unroll
    for (int q = 0; q < 4; ++q) {
      mrow[i][q] = -1e30f;
      lrow[i][q] = 0.f;
    }

  for (int m0 = 0; m0 < 256; m0 += 32) {
    f32x4 s[2][2] = {};
    s16x8 bk_[2];
#pragma unroll
    for (int j = 0; j < 2; ++j)
      bk_[j] = *(const s16x8*)&ks[m0 + j * 16 + l15][l4 * 8];
#pragma unroll
    for (int i = 0; i < 2; ++i)
#pragma unroll
      for (int j = 0; j < 2; ++j)
        s[i][j] = mfma_bf16(aq[i], bk_[j], s[i][j]);
#pragma unroll
    for (int i = 0; i < 2; ++i) {
      float cm[4];
#pragma unroll
      for (int q = 0; q < 4; ++q) cm[q] = fmaxf(s[i][0][q], s[i][1][q]);
#pragma unroll
      for (int sh = 1; sh < 16; sh <<= 1)
#pragma unroll
        for (int q = 0; q < 4; ++q) cm[q] = fmaxf(cm[q], __shfl_xor(cm[q], sh));
      float al[4], ps[4];
#pragma unroll
      for (int q = 0; q < 4; ++q) {
        float mn = fmaxf(mrow[i][q], cm[q]);
        al[q] = __expf(mrow[i][q] - mn);
        mrow[i][q] = mn;
        float p0 = __expf(s[i][0][q] - mn);
        float p1 = __expf(s[i][1][q] - mn);
        s[i][0][q] = p0;
        s[i][1][q] = p1;
        ps[q] = p0 + p1;
      }
#pragma unroll
      for (int sh = 1; sh < 16; sh <<= 1)
#pragma unroll
        for (int q = 0; q < 4; ++q) ps[q] += __shfl_xor(ps[q], sh);
#pragma unroll
      for (int q = 0; q < 4; ++q) lrow[i][q] = lrow[i][q] * al[q] + ps[q];
#pragma unroll
      for (int jd = 0; jd < 2; ++jd)
#pragma unroll
        for (int q = 0; q < 4; ++q) O[i][jd][q] *= al[q];
#pragma unroll
      for (int j = 0; j < 2; ++j)
#pragma unroll
        for (int q = 0; q < 4; ++q)
          Ps[wave][i * 16 + l4 * 4 + q][j * 16 + l15] = f2b(s[i][j][q]);
    }
    s16x8 pa[2], bv[2];
#pragma unroll
    for (int i = 0; i < 2; ++i)
      pa[i] = *(const s16x8*)&Ps[wave][i * 16 + l15][l4 * 8];
#pragma unroll
    for (int jd = 0; jd < 2; ++jd)
      bv[jd] = *(const s16x8*)&vs[jd * 16 + l15][m0 + l4 * 8];
#pragma unroll
    for (int i = 0; i < 2; ++i)
#pragma unroll
      for (int jd = 0; jd < 2; ++jd)
        O[i][jd] = mfma_bf16(pa[i], bv[jd], O[i][jd]);
  }
  long rbase = base + half * 128 + r0;
#pragma unroll
  for (int i = 0; i < 2; ++i)
#pragma unroll
    for (int jd = 0; jd < 2; ++jd)
#pragma unroll
      for (int q = 0; q < 4; ++q)
        attN[(rbase + i * 16 + l4 * 4 + q) * 256 + h * 32 + jd * 16 + l15] =
            f2b(O[i][jd][q] / lrow[i][q]);
}

// ---------------- analytic BN stats (lowT f32 [1024][4096]) -----------------
__global__ __launch_bounds__(256) void stats_k(const float* __restrict__ low,
                                               const float* __restrict__ gamma,
                                               const float* __restrict__ beta,
                                               float* __restrict__ kA,
                                               float* __restrict__ kB) {
  int o = blockIdx.x, t = threadIdx.x;
  __shared__ float cw[16];
  __shared__ float A3[16][3];
  __shared__ float Ls[256];
  __shared__ float r1[4], r2[4];
  if (t < 16) {
    cw[t] = 0.f;
    A3[t][0] = A3[t][1] = A3[t][2] = 0.f;
  }
  __syncthreads();
  if (t < 64) {
    float src = 0.25f * t - 0.375f;
    float fl = floorf(src);
    float f = src - fl;
    int i0 = (int)fl, i1 = i0 + 1;
    i0 = max(0, min(15, i0));
    i1 = max(0, min(15, i1));
    float w0 = 1.f - f, w1 = f;
    atomicAdd(&cw[i0], w0);
    atomicAdd(&cw[i1], w1);
    if (i0 == i1)
      atomicAdd(&A3[i0][1], 1.f);
    else {
      atomicAdd(&A3[i0][1], w0 * w0);
      atomicAdd(&A3[i1][1], w1 * w1);
      atomicAdd(&A3[i0][2], w0 * w1);
      atomicAdd(&A3[i1][0], w0 * w1);
    }
  }
  __syncthreads();
  int i = t >> 4, j = t & 15;
  float s1 = 0.f, s2 = 0.f;
  for (int b = 0; b < 16; ++b) {
    Ls[t] = low[(long)o * 4096 + b * 256 + t];
    __syncthreads();
    float Lc = Ls[t];
    s1 += cw[i] * cw[j] * Lc;
    float a2 = 0.f;
#pragma unroll
    for (int di = -1; di <= 1; ++di) {
      int ii = max(0, min(15, i + di));
      float ay = A3[i][di + 1];
#pragma unroll
      for (int dj = -1; dj <= 1; ++dj) {
        int jj = max(0, min(15, j + dj));
        a2 += ay * A3[j][dj + 1] * Ls[ii * 16 + jj];
      }
    }
    s2 += a2 * Lc;
    __syncthreads();
  }
  int lane = t & 63, wid = t >> 6;
  for (int off = 32; off; off >>= 1) {
    s1 += __shfl_down(s1, off);
    s2 += __shfl_down(s2, off);
  }
  if (lane == 0) {
    r1[wid] = s1;
    r2[wid] = s2;
  }
  __syncthreads();
  if (t == 0) {
    s1 = r1[0] + r1[1] + r1[2] + r1[3];
    s2 = r2[0] + r2[1] + r2[2] + r2[3];
    float mean = s1 * (1.f / 65536.f);
    float var = s2 * (1.f / 65536.f) - mean * mean;
    float is = rsqrtf(var + 1e-5f);
    float g = gamma[o];
    kA[o] = g * is;
    kB[o] = beta[o] - mean * g * is;
  }
}

// ---------------- fused bilinear 4x upsample + BN affine --------------------
__global__ __launch_bounds__(256) void up_bn_k(const float* __restrict__ low,
                                               const float* __restrict__ kA,
                                               const float* __restrict__ kB,
                                               float* __restrict__ out) {
  long bo = blockIdx.x;               // b*1024 + o
  int b = (int)(bo >> 10), o = (int)(bo & 1023);
  int t = threadIdx.x;
  __shared__ float Ls[256];
  Ls[t] = low[(long)o * 4096 + b * 256 + t];
  __syncthreads();
  float a = kA[o], bb = kB[o];
  float* op = out + bo * 4096;
#pragma unroll
  for (int it = 0; it < 4; ++it) {
    int idx = it * 1024 + t * 4;
    int y = idx >> 6, x0 = idx & 63;
    float sy = 0.25f * y - 0.375f;
    float fly = floorf(sy);
    float fy = sy - fly;
    int y0 = max(0, min(15, (int)fly));
    int y1 = max(0, min(15, (int)fly + 1));
    const float* R0 = &Ls[y0 * 16];
    const float* R1 = &Ls[y1 * 16];
    float vout[4];
#pragma unroll
    for (int jj = 0; jj < 4; ++jj) {
      int xx = x0 + jj;
      float sx = 0.25f * xx - 0.375f;
      float flx = floorf(sx);
      float fx = sx - flx;
      int x0i = max(0, min(15, (int)flx));
      int x1i = max(0, min(15, (int)flx + 1));
      float v0 = R0[x0i] + fx * (R0[x1i] - R0[x0i]);
      float v1 = R1[x0i] + fx * (R1[x1i] - R1[x0i]);
      vout[jj] = a * (v0 + fy * (v1 - v0)) + bb;
    }
    float4 r;
    r.x = vout[0]; r.y = vout[1]; r.z = vout[2]; r.w = vout[3];
    *(float4*)(op + idx) = r;
  }
}

// ---------------------------------------------------------------------------
extern "C" void kernel_launch(void* const* d_in, const int* in_sizes, int n_in,
                              void* d_out, int out_size, void* d_ws,
                              size_t ws_size, hipStream_t stream) {
  const float* x = (const float*)d_in[0];
  const float* w_qkv = (const float*)d_in[1];
  const float* temp = (const float*)d_in[2];
  const float* w_proj = (const float*)d_in[3];
  const float* gamma = (const float*)d_in[4];
  const float* beta = (const float*)d_in[5];
  float* out = (float*)d_out;
  char* w = (char*)d_ws;

  u16* wqkv_b = (u16*)(w);                 // 1.50 MB
  u16* wproj_b = (u16*)(w + 1572864);      // 0.50 MB
  u16* xrN = (u16*)(w + 2097152);          // 8.0 MB  [4096][1024]
  u16* qkvb = (u16*)(w + 10485760);        // 6.0 MB  [768][4096]
  u16* attN = (u16*)(w + 16777216);        // 2.0 MB  [4096][256]
  float* lowT = (float*)(w + 18874368);    // 16 MB   [1024][4096]
  float* kA = (float*)(w + 35651584);
  float* kB = (float*)(w + 35655680);

  // 1) weights->bf16 + pool in one launch
  cvtpool_k<<<17408, 256, 0, stream>>>(w_qkv, wqkv_b, 196608, w_proj, wproj_b,
                                       65536, x, xrN);
  // 2) qkv GEMM: M=768,N=4096,K=1024
  mgemm_k<true><<<dim3(32, 6), 256, 0, stream>>>(wqkv_b, xrN, qkvb, 1024, 1024,
                                                 1024, 4096);
  // 3) fused attention -> attN
  attn_k<<<256, 256, 0, stream>>>(qkvb, temp, attN);
  // 4) proj GEMM at low res: M=1024,N=4096,K=256
  mgemm_k<false><<<dim3(32, 8), 256, 0, stream>>>(wproj_b, attN, lowT, 256, 256,
                                                  256, 4096);
  // 5) analytic BN stats
  stats_k<<<1024, 256, 0, stream>>>(lowT, gamma, beta, kA, kB);
  // 6) fused upsample + BN -> out
  up_bn_k<<<16384, 256, 0, stream>>>(lowT, kA, kB, out);
}

// Round 7
// 172.690 us; speedup vs baseline: 1.2516x; 1.0090x over previous
//
#include <hip/hip_runtime.h>
#include <math.h>

// ---------------------------------------------------------------------------
// HMHA round 7: R6 + ONE change — mgemm BN 128->64 (templated).
//   Mechanism: qkv grid 192->384, proj 256->512 blocks; LDS 64->48 KB gives
//   3 blocks/CU so the per-iter vmcnt(0) barrier drain overlaps other blocks'
//   MFMA. Cost: A-panel re-reads double (L2-resident).
// ---------------------------------------------------------------------------

typedef unsigned short u16;
typedef u16 u16x8 __attribute__((ext_vector_type(8)));
typedef u16 u16x4 __attribute__((ext_vector_type(4)));
typedef short s16x8 __attribute__((ext_vector_type(8)));
typedef float f32x4 __attribute__((ext_vector_type(4)));

__device__ __forceinline__ float b2f(u16 u) {
  union { unsigned u; float f; } v;
  v.u = (unsigned)u << 16;
  return v.f;
}
__device__ __forceinline__ u16 f2b(float f) {
  union { float f; unsigned u; } v;
  v.f = f;
  unsigned r = (v.u + 0x7fffu + ((v.u >> 16) & 1u)) >> 16;
  return (u16)r;
}
__device__ __forceinline__ f32x4 mfma_bf16(s16x8 a, s16x8 b, f32x4 c) {
  return __builtin_amdgcn_mfma_f32_16x16x32_bf16(a, b, c, 0, 0, 0);
}
// global -> LDS direct 16B load (dest = wave-uniform base + lane*16)
__device__ __forceinline__ void gload16(const u16* g, u16* l) {
  unsigned loff = (unsigned)(unsigned long long)l;
  __builtin_amdgcn_global_load_lds(
      (const __attribute__((address_space(1))) void*)g,
      (__attribute__((address_space(3))) void*)loff, 16, 0, 0);
}

// ---------------- fused: weight cvt (blocks 0..1023) + pool (rest) ----------
__global__ __launch_bounds__(256) void cvtpool_k(
    const float* __restrict__ wa, u16* __restrict__ da, int n4a,
    const float* __restrict__ wb, u16* __restrict__ db, int n4b,
    const float* __restrict__ x, u16* __restrict__ xrN) {
  int bid = blockIdx.x;
  if (bid < 1024) {
    int idx = bid * 256 + threadIdx.x;
    const float* s;
    u16* d;
    if (idx < n4a) {
      s = wa; d = da;
    } else {
      idx -= n4a;
      if (idx >= n4b) return;
      s = wb; d = db;
    }
    float4 v = ((const float4*)s)[idx];
    u16x4 o;
    o.x = f2b(v.x); o.y = f2b(v.y); o.z = f2b(v.z); o.w = f2b(v.w);
    ((u16x4*)d)[idx] = o;
    return;
  }
  bid -= 1024;
  int g = bid >> 3, xcd = bid & 7;
  int c = xcd * 128 + (g & 127);
  int b = g >> 7;
  int t = threadIdx.x;
  int i = t >> 4, j = t & 15;
  const float* p = x + ((long)(b * 1024 + c)) * 4096 + (long)i * 256 + j * 4;
  float s = 0.f;
#pragma unroll
  for (int r = 0; r < 4; ++r) {
    float4 v = *(const float4*)(p + r * 64);
    s += v.x + v.y + v.z + v.w;
  }
  xrN[((long)(b << 8) + t) * 1024 + c] = f2b(s * 0.0625f);
}

// ---------------- MFMA GEMM, double-buffered, gload_lds + XOR swizzle -------
// C[M][N] = A[M][K] * B[N][K]^T. BMx BN tile, BK=64, 4 waves (2x2 grid),
// wave tile (BM/2)x(BN/2), frags FM=BM/32 x FN=BN/32.
// LDS chunk(16B) swizzle: phys = logical ^ (row&7), same involution applied
// on the global source chunk and the ds_read chunk (both-sides rule).
template <int BM, int BN, bool OUT_BF16>
__global__ __launch_bounds__(256) void mgemm_k(const u16* __restrict__ A,
                                               const u16* __restrict__ B,
                                               void* __restrict__ C, int K,
                                               int lda, int ldb, int ldc) {
  constexpr int BK = 64;
  constexpr int FM = BM / 32, FN = BN / 32;
  __shared__ u16 As[2][BM * BK];
  __shared__ u16 Bs[2][BN * BK];
  const int t = threadIdx.x;
  const int lane = t & 63, wave = t >> 6;
  const int l15 = lane & 15, l4 = lane >> 4;
  const int row0 = blockIdx.y * BM, col0 = blockIdx.x * BN;
  const int wr = (wave >> 1) * (BM / 2), wc = (wave & 1) * (BN / 2);
  const int srow = t >> 3;               // staging row within a 32-row pass
  const int sch = (t & 7) ^ (srow & 7);  // swizzled source chunk
  f32x4 acc[FM][FN] = {};

  auto STG = [&](int buf, int k0) {
#pragma unroll
    for (int p = 0; p < BM / 32; ++p)
      gload16(&A[(long)(row0 + p * 32 + srow) * lda + k0 + sch * 8],
              &As[buf][(p * 256 + wave * 64) * 8]);
#pragma unroll
    for (int p = 0; p < BN / 32; ++p)
      gload16(&B[(long)(col0 + p * 32 + srow) * ldb + k0 + sch * 8],
              &Bs[buf][(p * 256 + wave * 64) * 8]);
  };
  auto COMP = [&](int buf) {
#pragma unroll
    for (int kk = 0; kk < BK / 32; ++kk) {
      s16x8 a[FM], bfr[FN];
#pragma unroll
      for (int i = 0; i < FM; i++) {
        int r = wr + i * 16 + l15;
        int ph = (kk * 4 + l4) ^ (r & 7);
        a[i] = *(const s16x8*)&As[buf][r * 64 + ph * 8];
      }
#pragma unroll
      for (int j = 0; j < FN; j++) {
        int r = wc + j * 16 + l15;
        int ph = (kk * 4 + l4) ^ (r & 7);
        bfr[j] = *(const s16x8*)&Bs[buf][r * 64 + ph * 8];
      }
#pragma unroll
      for (int i = 0; i < FM; i++)
#pragma unroll
        for (int j = 0; j < FN; j++)
          acc[i][j] = mfma_bf16(a[i], bfr[j], acc[i][j]);
    }
  };

  STG(0, 0);
  __syncthreads();          // drains vmcnt(0): buf0 ready
  int cur = 0;
  for (int k0 = BK; k0 < K; k0 += BK) {
    STG(cur ^ 1, k0);       // issue next tile while computing current
    COMP(cur);
    __syncthreads();        // one barrier per iter (drains staging)
    cur ^= 1;
  }
  COMP(cur);

#pragma unroll
  for (int i = 0; i < FM; i++)
#pragma unroll
    for (int j = 0; j < FN; j++)
#pragma unroll
      for (int q = 0; q < 4; q++) {
        long r = row0 + wr + i * 16 + l4 * 4 + q;
        long c = col0 + wc + j * 16 + l15;
        if constexpr (OUT_BF16)
          ((u16*)C)[r * ldc + c] = f2b(acc[i][j][q]);
        else
          ((float*)C)[r * ldc + c] = acc[i][j][q];
      }
}

// ---------------- fused attention: norm + QK^T + softmax + PV ---------------
__global__ __launch_bounds__(256) void attn_k(const u16* __restrict__ qkv,
                                              const float* __restrict__ temp,
                                              u16* __restrict__ attN) {
  int blk = blockIdx.x;
  int bh = blk >> 1, half = blk & 1;
  int b = bh >> 3, h = bh & 7;
  __shared__ u16 qs[128][40];
  __shared__ u16 ks[256][40];
  __shared__ u16 vs[32][264];
  __shared__ u16 Ps[4][32][40];
  int t = threadIdx.x, lane = t & 63, wave = t >> 6;
  int l15 = lane & 15, l4 = lane >> 4;
  long base = (long)b * 256;

  {
    const u16* V = qkv + (long)(512 + h * 32) * 4096 + base;
#pragma unroll
    for (int p = 0; p < 4; ++p) {
      int c = p * 256 + t;
      int row = c >> 5, off = (c & 31) * 8;
      *(u16x8*)&vs[row][off] = *(const u16x8*)&V[(long)row * 4096 + off];
    }
  }
  {
    const u16* Kp = qkv + (long)(256 + h * 32) * 4096 + base + t;
    float v[32], ss = 0.f;
#pragma unroll
    for (int d = 0; d < 32; ++d) {
      v[d] = b2f(Kp[(long)d * 4096]);
      ss += v[d] * v[d];
    }
    float sc = 1.f / fmaxf(sqrtf(ss), 1e-12f);
#pragma unroll
    for (int d = 0; d < 32; ++d) ks[t][d] = f2b(v[d] * sc);
  }
  if (t < 128) {
    const u16* Qp = qkv + (long)(h * 32) * 4096 + base + half * 128 + t;
    float v[32], ss = 0.f;
#pragma unroll
    for (int d = 0; d < 32; ++d) {
      v[d] = b2f(Qp[(long)d * 4096]);
      ss += v[d] * v[d];
    }
    float sc = temp[h] / fmaxf(sqrtf(ss), 1e-12f);
#pragma unroll
    for (int d = 0; d < 32; ++d) qs[t][d] = f2b(v[d] * sc);
  }
  __syncthreads();

  int r0 = wave * 32;
  s16x8 aq[2];
#pragma unroll
  for (int i = 0; i < 2; ++i)
    aq[i] = *(const s16x8*)&qs[r0 + i * 16 + l15][l4 * 8];
  f32x4 O[2][2] = {};
  float mrow[2][4], lrow[2][4];
#pragma unroll
  for (int i = 0; i < 2; ++i)
#pragma unroll
    for (int q = 0; q < 4; ++q) {
      mrow[i][q] = -1e30f;
      lrow[i][q] = 0.f;
    }

  for (int m0 = 0; m0 < 256; m0 += 32) {
    f32x4 s[2][2] = {};
    s16x8 bk_[2];
#pragma unroll
    for (int j = 0; j < 2; ++j)
      bk_[j] = *(const s16x8*)&ks[m0 + j * 16 + l15][l4 * 8];
#pragma unroll
    for (int i = 0; i < 2; ++i)
#pragma unroll
      for (int j = 0; j < 2; ++j)
        s[i][j] = mfma_bf16(aq[i], bk_[j], s[i][j]);
#pragma unroll
    for (int i = 0; i < 2; ++i) {
      float cm[4];
#pragma unroll
      for (int q = 0; q < 4; ++q) cm[q] = fmaxf(s[i][0][q], s[i][1][q]);
#pragma unroll
      for (int sh = 1; sh < 16; sh <<= 1)
#pragma unroll
        for (int q = 0; q < 4; ++q) cm[q] = fmaxf(cm[q], __shfl_xor(cm[q], sh));
      float al[4], ps[4];
#pragma unroll
      for (int q = 0; q < 4; ++q) {
        float mn = fmaxf(mrow[i][q], cm[q]);
        al[q] = __expf(mrow[i][q] - mn);
        mrow[i][q] = mn;
        float p0 = __expf(s[i][0][q] - mn);
        float p1 = __expf(s[i][1][q] - mn);
        s[i][0][q] = p0;
        s[i][1][q] = p1;
        ps[q] = p0 + p1;
      }
#pragma unroll
      for (int sh = 1; sh < 16; sh <<= 1)
#pragma unroll
        for (int q = 0; q < 4; ++q) ps[q] += __shfl_xor(ps[q], sh);
#pragma unroll
      for (int q = 0; q < 4; ++q) lrow[i][q] = lrow[i][q] * al[q] + ps[q];
#pragma unroll
      for (int jd = 0; jd < 2; ++jd)
#pragma unroll
        for (int q = 0; q < 4; ++q) O[i][jd][q] *= al[q];
#pragma unroll
      for (int j = 0; j < 2; ++j)
#pragma unroll
        for (int q = 0; q < 4; ++q)
          Ps[wave][i * 16 + l4 * 4 + q][j * 16 + l15] = f2b(s[i][j][q]);
    }
    s16x8 pa[2], bv[2];
#pragma unroll
    for (int i = 0; i < 2; ++i)
      pa[i] = *(const s16x8*)&Ps[wave][i * 16 + l15][l4 * 8];
#pragma unroll
    for (int jd = 0; jd < 2; ++jd)
      bv[jd] = *(const s16x8*)&vs[jd * 16 + l15][m0 + l4 * 8];
#pragma unroll
    for (int i = 0; i < 2; ++i)
#pragma unroll
      for (int jd = 0; jd < 2; ++jd)
        O[i][jd] = mfma_bf16(pa[i], bv[jd], O[i][jd]);
  }
  long rbase = base + half * 128 + r0;
#pragma unroll
  for (int i = 0; i < 2; ++i)
#pragma unroll
    for (int jd = 0; jd < 2; ++jd)
#pragma unroll
      for (int q = 0; q < 4; ++q)
        attN[(rbase + i * 16 + l4 * 4 + q) * 256 + h * 32 + jd * 16 + l15] =
            f2b(O[i][jd][q] / lrow[i][q]);
}

// ---------------- analytic BN stats (lowT f32 [1024][4096]) -----------------
__global__ __launch_bounds__(256) void stats_k(const float* __restrict__ low,
                                               const float* __restrict__ gamma,
                                               const float* __restrict__ beta,
                                               float* __restrict__ kA,
                                               float* __restrict__ kB) {
  int o = blockIdx.x, t = threadIdx.x;
  __shared__ float cw[16];
  __shared__ float A3[16][3];
  __shared__ float Ls[256];
  __shared__ float r1[4], r2[4];
  if (t < 16) {
    cw[t] = 0.f;
    A3[t][0] = A3[t][1] = A3[t][2] = 0.f;
  }
  __syncthreads();
  if (t < 64) {
    float src = 0.25f * t - 0.375f;
    float fl = floorf(src);
    float f = src - fl;
    int i0 = (int)fl, i1 = i0 + 1;
    i0 = max(0, min(15, i0));
    i1 = max(0, min(15, i1));
    float w0 = 1.f - f, w1 = f;
    atomicAdd(&cw[i0], w0);
    atomicAdd(&cw[i1], w1);
    if (i0 == i1)
      atomicAdd(&A3[i0][1], 1.f);
    else {
      atomicAdd(&A3[i0][1], w0 * w0);
      atomicAdd(&A3[i1][1], w1 * w1);
      atomicAdd(&A3[i0][2], w0 * w1);
      atomicAdd(&A3[i1][0], w0 * w1);
    }
  }
  __syncthreads();
  int i = t >> 4, j = t & 15;
  float s1 = 0.f, s2 = 0.f;
  for (int b = 0; b < 16; ++b) {
    Ls[t] = low[(long)o * 4096 + b * 256 + t];
    __syncthreads();
    float Lc = Ls[t];
    s1 += cw[i] * cw[j] * Lc;
    float a2 = 0.f;
#pragma unroll
    for (int di = -1; di <= 1; ++di) {
      int ii = max(0, min(15, i + di));
      float ay = A3[i][di + 1];
#pragma unroll
      for (int dj = -1; dj <= 1; ++dj) {
        int jj = max(0, min(15, j + dj));
        a2 += ay * A3[j][dj + 1] * Ls[ii * 16 + jj];
      }
    }
    s2 += a2 * Lc;
    __syncthreads();
  }
  int lane = t & 63, wid = t >> 6;
  for (int off = 32; off; off >>= 1) {
    s1 += __shfl_down(s1, off);
    s2 += __shfl_down(s2, off);
  }
  if (lane == 0) {
    r1[wid] = s1;
    r2[wid] = s2;
  }
  __syncthreads();
  if (t == 0) {
    s1 = r1[0] + r1[1] + r1[2] + r1[3];
    s2 = r2[0] + r2[1] + r2[2] + r2[3];
    float mean = s1 * (1.f / 65536.f);
    float var = s2 * (1.f / 65536.f) - mean * mean;
    float is = rsqrtf(var + 1e-5f);
    float g = gamma[o];
    kA[o] = g * is;
    kB[o] = beta[o] - mean * g * is;
  }
}

// ---------------- fused bilinear 4x upsample + BN affine --------------------
__global__ __launch_bounds__(256) void up_bn_k(const float* __restrict__ low,
                                               const float* __restrict__ kA,
                                               const float* __restrict__ kB,
                                               float* __restrict__ out) {
  long bo = blockIdx.x;               // b*1024 + o
  int b = (int)(bo >> 10), o = (int)(bo & 1023);
  int t = threadIdx.x;
  __shared__ float Ls[256];
  Ls[t] = low[(long)o * 4096 + b * 256 + t];
  __syncthreads();
  float a = kA[o], bb = kB[o];
  float* op = out + bo * 4096;
#pragma unroll
  for (int it = 0; it < 4; ++it) {
    int idx = it * 1024 + t * 4;
    int y = idx >> 6, x0 = idx & 63;
    float sy = 0.25f * y - 0.375f;
    float fly = floorf(sy);
    float fy = sy - fly;
    int y0 = max(0, min(15, (int)fly));
    int y1 = max(0, min(15, (int)fly + 1));
    const float* R0 = &Ls[y0 * 16];
    const float* R1 = &Ls[y1 * 16];
    float vout[4];
#pragma unroll
    for (int jj = 0; jj < 4; ++jj) {
      int xx = x0 + jj;
      float sx = 0.25f * xx - 0.375f;
      float flx = floorf(sx);
      float fx = sx - flx;
      int x0i = max(0, min(15, (int)flx));
      int x1i = max(0, min(15, (int)flx + 1));
      float v0 = R0[x0i] + fx * (R0[x1i] - R0[x0i]);
      float v1 = R1[x0i] + fx * (R1[x1i] - R1[x0i]);
      vout[jj] = a * (v0 + fy * (v1 - v0)) + bb;
    }
    float4 r;
    r.x = vout[0]; r.y = vout[1]; r.z = vout[2]; r.w = vout[3];
    *(float4*)(op + idx) = r;
  }
}

// ---------------------------------------------------------------------------
extern "C" void kernel_launch(void* const* d_in, const int* in_sizes, int n_in,
                              void* d_out, int out_size, void* d_ws,
                              size_t ws_size, hipStream_t stream) {
  const float* x = (const float*)d_in[0];
  const float* w_qkv = (const float*)d_in[1];
  const float* temp = (const float*)d_in[2];
  const float* w_proj = (const float*)d_in[3];
  const float* gamma = (const float*)d_in[4];
  const float* beta = (const float*)d_in[5];
  float* out = (float*)d_out;
  char* w = (char*)d_ws;

  u16* wqkv_b = (u16*)(w);                 // 1.50 MB
  u16* wproj_b = (u16*)(w + 1572864);      // 0.50 MB
  u16* xrN = (u16*)(w + 2097152);          // 8.0 MB  [4096][1024]
  u16* qkvb = (u16*)(w + 10485760);        // 6.0 MB  [768][4096]
  u16* attN = (u16*)(w + 16777216);        // 2.0 MB  [4096][256]
  float* lowT = (float*)(w + 18874368);    // 16 MB   [1024][4096]
  float* kA = (float*)(w + 35651584);
  float* kB = (float*)(w + 35655680);

  // 1) weights->bf16 + pool in one launch
  cvtpool_k<<<17408, 256, 0, stream>>>(w_qkv, wqkv_b, 196608, w_proj, wproj_b,
                                       65536, x, xrN);
  // 2) qkv GEMM: M=768,N=4096,K=1024  (384 blocks, 3/CU resident)
  mgemm_k<128, 64, true><<<dim3(64, 6), 256, 0, stream>>>(
      wqkv_b, xrN, qkvb, 1024, 1024, 1024, 4096);
  // 3) fused attention -> attN
  attn_k<<<256, 256, 0, stream>>>(qkvb, temp, attN);
  // 4) proj GEMM at low res: M=1024,N=4096,K=256  (512 blocks)
  mgemm_k<128, 64, false><<<dim3(64, 8), 256, 0, stream>>>(
      wproj_b, attN, lowT, 256, 256, 256, 4096);
  // 5) analytic BN stats
  stats_k<<<1024, 256, 0, stream>>>(lowT, gamma, beta, kA, kB);
  // 6) fused upsample + BN -> out
  up_bn_k<<<16384, 256, 0, stream>>>(lowT, kA, kB, out);
}

// Round 8
// 168.935 us; speedup vs baseline: 1.2794x; 1.0222x over previous
//
#include <hip/hip_runtime.h>
#include <math.h>

// ---------------------------------------------------------------------------
// HMHA round 8: R7 + two latency-hiding fixes (independent kernels):
//   - attn_k: 256->512 blocks (bh x quarter, 64 q-rows, 4 waves x 16 rows).
//     2 waves/SIMD TLP; per-wave serial softmax chain halved. Bitwise-same
//     row arithmetic. Quarters of one bh spaced 128 apart -> same XCD.
//   - stats_k: preload all 16 batches to LDS once (validated statsup phase 1),
//     removing 32 barriers + 16 serial 1KB-load round-trips.
//   - everything else identical to R7 (172.7 us).
// ---------------------------------------------------------------------------

typedef unsigned short u16;
typedef u16 u16x8 __attribute__((ext_vector_type(8)));
typedef u16 u16x4 __attribute__((ext_vector_type(4)));
typedef short s16x8 __attribute__((ext_vector_type(8)));
typedef float f32x4 __attribute__((ext_vector_type(4)));

__device__ __forceinline__ float b2f(u16 u) {
  union { unsigned u; float f; } v;
  v.u = (unsigned)u << 16;
  return v.f;
}
__device__ __forceinline__ u16 f2b(float f) {
  union { float f; unsigned u; } v;
  v.f = f;
  unsigned r = (v.u + 0x7fffu + ((v.u >> 16) & 1u)) >> 16;
  return (u16)r;
}
__device__ __forceinline__ f32x4 mfma_bf16(s16x8 a, s16x8 b, f32x4 c) {
  return __builtin_amdgcn_mfma_f32_16x16x32_bf16(a, b, c, 0, 0, 0);
}
// global -> LDS direct 16B load (dest = wave-uniform base + lane*16)
__device__ __forceinline__ void gload16(const u16* g, u16* l) {
  unsigned loff = (unsigned)(unsigned long long)l;
  __builtin_amdgcn_global_load_lds(
      (const __attribute__((address_space(1))) void*)g,
      (__attribute__((address_space(3))) void*)loff, 16, 0, 0);
}

// ---------------- fused: weight cvt (blocks 0..1023) + pool (rest) ----------
__global__ __launch_bounds__(256) void cvtpool_k(
    const float* __restrict__ wa, u16* __restrict__ da, int n4a,
    const float* __restrict__ wb, u16* __restrict__ db, int n4b,
    const float* __restrict__ x, u16* __restrict__ xrN) {
  int bid = blockIdx.x;
  if (bid < 1024) {
    int idx = bid * 256 + threadIdx.x;
    const float* s;
    u16* d;
    if (idx < n4a) {
      s = wa; d = da;
    } else {
      idx -= n4a;
      if (idx >= n4b) return;
      s = wb; d = db;
    }
    float4 v = ((const float4*)s)[idx];
    u16x4 o;
    o.x = f2b(v.x); o.y = f2b(v.y); o.z = f2b(v.z); o.w = f2b(v.w);
    ((u16x4*)d)[idx] = o;
    return;
  }
  bid -= 1024;
  int g = bid >> 3, xcd = bid & 7;
  int c = xcd * 128 + (g & 127);
  int b = g >> 7;
  int t = threadIdx.x;
  int i = t >> 4, j = t & 15;
  const float* p = x + ((long)(b * 1024 + c)) * 4096 + (long)i * 256 + j * 4;
  float s = 0.f;
#pragma unroll
  for (int r = 0; r < 4; ++r) {
    float4 v = *(const float4*)(p + r * 64);
    s += v.x + v.y + v.z + v.w;
  }
  xrN[((long)(b << 8) + t) * 1024 + c] = f2b(s * 0.0625f);
}

// ---------------- MFMA GEMM, double-buffered, gload_lds + XOR swizzle -------
// C[M][N] = A[M][K] * B[N][K]^T. BMxBN tile, BK=64, 4 waves (2x2 grid).
template <int BM, int BN, bool OUT_BF16>
__global__ __launch_bounds__(256) void mgemm_k(const u16* __restrict__ A,
                                               const u16* __restrict__ B,
                                               void* __restrict__ C, int K,
                                               int lda, int ldb, int ldc) {
  constexpr int BK = 64;
  constexpr int FM = BM / 32, FN = BN / 32;
  __shared__ u16 As[2][BM * BK];
  __shared__ u16 Bs[2][BN * BK];
  const int t = threadIdx.x;
  const int lane = t & 63, wave = t >> 6;
  const int l15 = lane & 15, l4 = lane >> 4;
  const int row0 = blockIdx.y * BM, col0 = blockIdx.x * BN;
  const int wr = (wave >> 1) * (BM / 2), wc = (wave & 1) * (BN / 2);
  const int srow = t >> 3;               // staging row within a 32-row pass
  const int sch = (t & 7) ^ (srow & 7);  // swizzled source chunk
  f32x4 acc[FM][FN] = {};

  auto STG = [&](int buf, int k0) {
#pragma unroll
    for (int p = 0; p < BM / 32; ++p)
      gload16(&A[(long)(row0 + p * 32 + srow) * lda + k0 + sch * 8],
              &As[buf][(p * 256 + wave * 64) * 8]);
#pragma unroll
    for (int p = 0; p < BN / 32; ++p)
      gload16(&B[(long)(col0 + p * 32 + srow) * ldb + k0 + sch * 8],
              &Bs[buf][(p * 256 + wave * 64) * 8]);
  };
  auto COMP = [&](int buf) {
#pragma unroll
    for (int kk = 0; kk < BK / 32; ++kk) {
      s16x8 a[FM], bfr[FN];
#pragma unroll
      for (int i = 0; i < FM; i++) {
        int r = wr + i * 16 + l15;
        int ph = (kk * 4 + l4) ^ (r & 7);
        a[i] = *(const s16x8*)&As[buf][r * 64 + ph * 8];
      }
#pragma unroll
      for (int j = 0; j < FN; j++) {
        int r = wc + j * 16 + l15;
        int ph = (kk * 4 + l4) ^ (r & 7);
        bfr[j] = *(const s16x8*)&Bs[buf][r * 64 + ph * 8];
      }
#pragma unroll
      for (int i = 0; i < FM; i++)
#pragma unroll
        for (int j = 0; j < FN; j++)
          acc[i][j] = mfma_bf16(a[i], bfr[j], acc[i][j]);
    }
  };

  STG(0, 0);
  __syncthreads();          // drains vmcnt(0): buf0 ready
  int cur = 0;
  for (int k0 = BK; k0 < K; k0 += BK) {
    STG(cur ^ 1, k0);       // issue next tile while computing current
    COMP(cur);
    __syncthreads();        // one barrier per iter (drains staging)
    cur ^= 1;
  }
  COMP(cur);

#pragma unroll
  for (int i = 0; i < FM; i++)
#pragma unroll
    for (int j = 0; j < FN; j++)
#pragma unroll
      for (int q = 0; q < 4; q++) {
        long r = row0 + wr + i * 16 + l4 * 4 + q;
        long c = col0 + wc + j * 16 + l15;
        if constexpr (OUT_BF16)
          ((u16*)C)[r * ldc + c] = f2b(acc[i][j][q]);
        else
          ((float*)C)[r * ldc + c] = acc[i][j][q];
      }
}

// ---------------- fused attention: norm + QK^T + softmax + PV ---------------
// grid 512: blk -> bh = blk&127, quarter = blk>>7 (quarters of one bh are
// spaced 128 apart -> same XCD under round-robin; share K/V L2 lines).
// 4 waves x 16 q-rows; 2 waves/SIMD device-wide for latency hiding.
__global__ __launch_bounds__(256) void attn_k(const u16* __restrict__ qkv,
                                              const float* __restrict__ temp,
                                              u16* __restrict__ attN) {
  int blk = blockIdx.x;
  int bh = blk & 127, quar = blk >> 7;
  int b = bh >> 3, h = bh & 7;
  __shared__ u16 qs[64][40];    // this quarter's q rows, l2-normed * temp
  __shared__ u16 ks[256][40];   // all keys, l2-normed
  __shared__ u16 vs[32][264];   // V^T [d][m]
  __shared__ u16 Ps[4][16][40]; // per-wave P chunk transpose buffer
  int t = threadIdx.x, lane = t & 63, wave = t >> 6;
  int l15 = lane & 15, l4 = lane >> 4;
  long base = (long)b * 256;

  {  // stage V^T rows (contiguous in qkv)
    const u16* V = qkv + (long)(512 + h * 32) * 4096 + base;
#pragma unroll
    for (int p = 0; p < 4; ++p) {
      int c = p * 256 + t;
      int row = c >> 5, off = (c & 31) * 8;
      *(u16x8*)&vs[row][off] = *(const u16x8*)&V[(long)row * 4096 + off];
    }
  }
  {  // stage K with l2norm: thread t owns key l=t
    const u16* Kp = qkv + (long)(256 + h * 32) * 4096 + base + t;
    float v[32], ss = 0.f;
#pragma unroll
    for (int d = 0; d < 32; ++d) {
      v[d] = b2f(Kp[(long)d * 4096]);
      ss += v[d] * v[d];
    }
    float sc = 1.f / fmaxf(sqrtf(ss), 1e-12f);
#pragma unroll
    for (int d = 0; d < 32; ++d) ks[t][d] = f2b(v[d] * sc);
  }
  if (t < 64) {  // stage this quarter's Q with l2norm * temperature
    const u16* Qp = qkv + (long)(h * 32) * 4096 + base + quar * 64 + t;
    float v[32], ss = 0.f;
#pragma unroll
    for (int d = 0; d < 32; ++d) {
      v[d] = b2f(Qp[(long)d * 4096]);
      ss += v[d] * v[d];
    }
    float sc = temp[h] / fmaxf(sqrtf(ss), 1e-12f);
#pragma unroll
    for (int d = 0; d < 32; ++d) qs[t][d] = f2b(v[d] * sc);
  }
  __syncthreads();

  int r0 = wave * 16;
  s16x8 aq = *(const s16x8*)&qs[r0 + l15][l4 * 8];
  f32x4 O[2] = {};
  float mrow[4], lrow[4];
#pragma unroll
  for (int q = 0; q < 4; ++q) {
    mrow[q] = -1e30f;
    lrow[q] = 0.f;
  }

  for (int m0 = 0; m0 < 256; m0 += 32) {
    // S chunk = q(16 rows) . k(32 keys)^T : 2 MFMA
    f32x4 s[2] = {};
    s16x8 bk_[2];
#pragma unroll
    for (int j = 0; j < 2; ++j)
      bk_[j] = *(const s16x8*)&ks[m0 + j * 16 + l15][l4 * 8];
#pragma unroll
    for (int j = 0; j < 2; ++j) s[j] = mfma_bf16(aq, bk_[j], s[j]);
    // online softmax per row q; row cols live in l15 x j
    float cm[4];
#pragma unroll
    for (int q = 0; q < 4; ++q) cm[q] = fmaxf(s[0][q], s[1][q]);
#pragma unroll
    for (int sh = 1; sh < 16; sh <<= 1)
#pragma unroll
      for (int q = 0; q < 4; ++q) cm[q] = fmaxf(cm[q], __shfl_xor(cm[q], sh));
    float al[4], ps[4];
#pragma unroll
    for (int q = 0; q < 4; ++q) {
      float mn = fmaxf(mrow[q], cm[q]);
      al[q] = __expf(mrow[q] - mn);
      mrow[q] = mn;
      float p0 = __expf(s[0][q] - mn);
      float p1 = __expf(s[1][q] - mn);
      s[0][q] = p0;
      s[1][q] = p1;
      ps[q] = p0 + p1;
    }
#pragma unroll
    for (int sh = 1; sh < 16; sh <<= 1)
#pragma unroll
      for (int q = 0; q < 4; ++q) ps[q] += __shfl_xor(ps[q], sh);
#pragma unroll
    for (int q = 0; q < 4; ++q) lrow[q] = lrow[q] * al[q] + ps[q];
#pragma unroll
    for (int jd = 0; jd < 2; ++jd)
#pragma unroll
      for (int q = 0; q < 4; ++q) O[jd][q] *= al[q];
    // transpose P chunk into LDS (C-layout -> A-fragment layout)
#pragma unroll
    for (int j = 0; j < 2; ++j)
#pragma unroll
      for (int q = 0; q < 4; ++q)
        Ps[wave][l4 * 4 + q][j * 16 + l15] = f2b(s[j][q]);
    // PV: O += P(16q x 32m) . V(32m x 32d)
    s16x8 pa = *(const s16x8*)&Ps[wave][l15][l4 * 8];
    s16x8 bv[2];
#pragma unroll
    for (int jd = 0; jd < 2; ++jd)
      bv[jd] = *(const s16x8*)&vs[jd * 16 + l15][m0 + l4 * 8];
#pragma unroll
    for (int jd = 0; jd < 2; ++jd) O[jd] = mfma_bf16(pa, bv[jd], O[jd]);
  }
  // epilogue: 1/l scale, write attN [b*256+l][h*32+d]
  long rbase = base + quar * 64 + r0;
#pragma unroll
  for (int jd = 0; jd < 2; ++jd)
#pragma unroll
    for (int q = 0; q < 4; ++q)
      attN[(rbase + l4 * 4 + q) * 256 + h * 32 + jd * 16 + l15] =
          f2b(O[jd][q] / lrow[q]);
}

// ---------------- analytic BN stats, preload-all variant --------------------
// grid 1024 = one block per channel o. Load all 16 batches (16 KB) once,
// ONE barrier, then barrier-free quadratic-form compute (statsup phase 1).
__global__ __launch_bounds__(256) void stats_k(const float* __restrict__ low,
                                               const float* __restrict__ gamma,
                                               const float* __restrict__ beta,
                                               float* __restrict__ kA,
                                               float* __restrict__ kB) {
  int o = blockIdx.x, t = threadIdx.x;
  __shared__ float Lall[16][256];
  __shared__ float cw[16];
  __shared__ float A3[16][3];
  __shared__ float r1[4], r2[4];

#pragma unroll
  for (int q = 0; q < 4; ++q) {
    float4 v = ((const float4*)(low + (long)o * 4096))[q * 256 + t];
    int b = q * 4 + (t >> 6), pix = (t & 63) * 4;
    *(float4*)&Lall[b][pix] = v;
  }
  if (t < 16) {
    cw[t] = 0.f;
    A3[t][0] = A3[t][1] = A3[t][2] = 0.f;
  }
  __syncthreads();
  if (t < 64) {
    float src = 0.25f * t - 0.375f;
    float fl = floorf(src);
    float f = src - fl;
    int i0 = (int)fl, i1 = i0 + 1;
    i0 = max(0, min(15, i0));
    i1 = max(0, min(15, i1));
    float w0 = 1.f - f, w1 = f;
    atomicAdd(&cw[i0], w0);
    atomicAdd(&cw[i1], w1);
    if (i0 == i1)
      atomicAdd(&A3[i0][1], 1.f);
    else {
      atomicAdd(&A3[i0][1], w0 * w0);
      atomicAdd(&A3[i1][1], w1 * w1);
      atomicAdd(&A3[i0][2], w0 * w1);
      atomicAdd(&A3[i1][0], w0 * w1);
    }
  }
  __syncthreads();
  int i = t >> 4, j = t & 15;
  float s1 = 0.f, s2 = 0.f;
#pragma unroll 4
  for (int b = 0; b < 16; ++b) {
    float Lc = Lall[b][t];
    s1 += cw[i] * cw[j] * Lc;
    float a2 = 0.f;
#pragma unroll
    for (int di = -1; di <= 1; ++di) {
      int ii = max(0, min(15, i + di));
      float ay = A3[i][di + 1];
#pragma unroll
      for (int dj = -1; dj <= 1; ++dj) {
        int jj = max(0, min(15, j + dj));
        a2 += ay * A3[j][dj + 1] * Lall[b][ii * 16 + jj];
      }
    }
    s2 += a2 * Lc;
  }
  int lane = t & 63, wid = t >> 6;
  for (int off = 32; off; off >>= 1) {
    s1 += __shfl_down(s1, off);
    s2 += __shfl_down(s2, off);
  }
  if (lane == 0) {
    r1[wid] = s1;
    r2[wid] = s2;
  }
  __syncthreads();
  if (t == 0) {
    s1 = r1[0] + r1[1] + r1[2] + r1[3];
    s2 = r2[0] + r2[1] + r2[2] + r2[3];
    float mean = s1 * (1.f / 65536.f);
    float var = s2 * (1.f / 65536.f) - mean * mean;
    float is = rsqrtf(var + 1e-5f);
    float g = gamma[o];
    kA[o] = g * is;
    kB[o] = beta[o] - mean * g * is;
  }
}

// ---------------- fused bilinear 4x upsample + BN affine --------------------
__global__ __launch_bounds__(256) void up_bn_k(const float* __restrict__ low,
                                               const float* __restrict__ kA,
                                               const float* __restrict__ kB,
                                               float* __restrict__ out) {
  long bo = blockIdx.x;               // b*1024 + o
  int b = (int)(bo >> 10), o = (int)(bo & 1023);
  int t = threadIdx.x;
  __shared__ float Ls[256];
  Ls[t] = low[(long)o * 4096 + b * 256 + t];
  __syncthreads();
  float a = kA[o], bb = kB[o];
  float* op = out + bo * 4096;
#pragma unroll
  for (int it = 0; it < 4; ++it) {
    int idx = it * 1024 + t * 4;
    int y = idx >> 6, x0 = idx & 63;
    float sy = 0.25f * y - 0.375f;
    float fly = floorf(sy);
    float fy = sy - fly;
    int y0 = max(0, min(15, (int)fly));
    int y1 = max(0, min(15, (int)fly + 1));
    const float* R0 = &Ls[y0 * 16];
    const float* R1 = &Ls[y1 * 16];
    float vout[4];
#pragma unroll
    for (int jj = 0; jj < 4; ++jj) {
      int xx = x0 + jj;
      float sx = 0.25f * xx - 0.375f;
      float flx = floorf(sx);
      float fx = sx - flx;
      int x0i = max(0, min(15, (int)flx));
      int x1i = max(0, min(15, (int)flx + 1));
      float v0 = R0[x0i] + fx * (R0[x1i] - R0[x0i]);
      float v1 = R1[x0i] + fx * (R1[x1i] - R1[x0i]);
      vout[jj] = a * (v0 + fy * (v1 - v0)) + bb;
    }
    float4 r;
    r.x = vout[0]; r.y = vout[1]; r.z = vout[2]; r.w = vout[3];
    *(float4*)(op + idx) = r;
  }
}

// ---------------------------------------------------------------------------
extern "C" void kernel_launch(void* const* d_in, const int* in_sizes, int n_in,
                              void* d_out, int out_size, void* d_ws,
                              size_t ws_size, hipStream_t stream) {
  const float* x = (const float*)d_in[0];
  const float* w_qkv = (const float*)d_in[1];
  const float* temp = (const float*)d_in[2];
  const float* w_proj = (const float*)d_in[3];
  const float* gamma = (const float*)d_in[4];
  const float* beta = (const float*)d_in[5];
  float* out = (float*)d_out;
  char* w = (char*)d_ws;

  u16* wqkv_b = (u16*)(w);                 // 1.50 MB
  u16* wproj_b = (u16*)(w + 1572864);      // 0.50 MB
  u16* xrN = (u16*)(w + 2097152);          // 8.0 MB  [4096][1024]
  u16* qkvb = (u16*)(w + 10485760);        // 6.0 MB  [768][4096]
  u16* attN = (u16*)(w + 16777216);        // 2.0 MB  [4096][256]
  float* lowT = (float*)(w + 18874368);    // 16 MB   [1024][4096]
  float* kA = (float*)(w + 35651584);
  float* kB = (float*)(w + 35655680);

  // 1) weights->bf16 + pool in one launch
  cvtpool_k<<<17408, 256, 0, stream>>>(w_qkv, wqkv_b, 196608, w_proj, wproj_b,
                                       65536, x, xrN);
  // 2) qkv GEMM: M=768,N=4096,K=1024
  mgemm_k<128, 64, true><<<dim3(64, 6), 256, 0, stream>>>(
      wqkv_b, xrN, qkvb, 1024, 1024, 1024, 4096);
  // 3) fused attention -> attN (512 blocks: bh x quarter)
  attn_k<<<512, 256, 0, stream>>>(qkvb, temp, attN);
  // 4) proj GEMM at low res: M=1024,N=4096,K=256
  mgemm_k<128, 64, false><<<dim3(64, 8), 256, 0, stream>>>(
      wproj_b, attN, lowT, 256, 256, 256, 4096);
  // 5) analytic BN stats (preload-all, barrier-light)
  stats_k<<<1024, 256, 0, stream>>>(lowT, gamma, beta, kA, kB);
  // 6) fused upsample + BN -> out
  up_bn_k<<<16384, 256, 0, stream>>>(lowT, kA, kB, out);
}

// Round 9
// 164.976 us; speedup vs baseline: 1.3101x; 1.0240x over previous
//
#include <hip/hip_runtime.h>
#include <math.h>

// ---------------------------------------------------------------------------
// HMHA round 9: R8 + ONE change — lowT stored as bf16 (was f32).
//   Halves proj-write (16->8 MB), stats-read, up_bn-read: -24 MB traffic.
//   Precision: bf16 rounding of low (~0.4% rel) before BN; predicted absmax
//   <= 0.05 vs threshold 0.08 (R8 margin 0.031).
// ---------------------------------------------------------------------------

typedef unsigned short u16;
typedef u16 u16x8 __attribute__((ext_vector_type(8)));
typedef u16 u16x4 __attribute__((ext_vector_type(4)));
typedef short s16x8 __attribute__((ext_vector_type(8)));
typedef float f32x4 __attribute__((ext_vector_type(4)));

__device__ __forceinline__ float b2f(u16 u) {
  union { unsigned u; float f; } v;
  v.u = (unsigned)u << 16;
  return v.f;
}
__device__ __forceinline__ u16 f2b(float f) {
  union { float f; unsigned u; } v;
  v.f = f;
  unsigned r = (v.u + 0x7fffu + ((v.u >> 16) & 1u)) >> 16;
  return (u16)r;
}
__device__ __forceinline__ f32x4 mfma_bf16(s16x8 a, s16x8 b, f32x4 c) {
  return __builtin_amdgcn_mfma_f32_16x16x32_bf16(a, b, c, 0, 0, 0);
}
// global -> LDS direct 16B load (dest = wave-uniform base + lane*16)
__device__ __forceinline__ void gload16(const u16* g, u16* l) {
  unsigned loff = (unsigned)(unsigned long long)l;
  __builtin_amdgcn_global_load_lds(
      (const __attribute__((address_space(1))) void*)g,
      (__attribute__((address_space(3))) void*)loff, 16, 0, 0);
}

// ---------------- fused: weight cvt (blocks 0..1023) + pool (rest) ----------
__global__ __launch_bounds__(256) void cvtpool_k(
    const float* __restrict__ wa, u16* __restrict__ da, int n4a,
    const float* __restrict__ wb, u16* __restrict__ db, int n4b,
    const float* __restrict__ x, u16* __restrict__ xrN) {
  int bid = blockIdx.x;
  if (bid < 1024) {
    int idx = bid * 256 + threadIdx.x;
    const float* s;
    u16* d;
    if (idx < n4a) {
      s = wa; d = da;
    } else {
      idx -= n4a;
      if (idx >= n4b) return;
      s = wb; d = db;
    }
    float4 v = ((const float4*)s)[idx];
    u16x4 o;
    o.x = f2b(v.x); o.y = f2b(v.y); o.z = f2b(v.z); o.w = f2b(v.w);
    ((u16x4*)d)[idx] = o;
    return;
  }
  bid -= 1024;
  int g = bid >> 3, xcd = bid & 7;
  int c = xcd * 128 + (g & 127);
  int b = g >> 7;
  int t = threadIdx.x;
  int i = t >> 4, j = t & 15;
  const float* p = x + ((long)(b * 1024 + c)) * 4096 + (long)i * 256 + j * 4;
  float s = 0.f;
#pragma unroll
  for (int r = 0; r < 4; ++r) {
    float4 v = *(const float4*)(p + r * 64);
    s += v.x + v.y + v.z + v.w;
  }
  xrN[((long)(b << 8) + t) * 1024 + c] = f2b(s * 0.0625f);
}

// ---------------- MFMA GEMM, double-buffered, gload_lds + XOR swizzle -------
// C[M][N] = A[M][K] * B[N][K]^T. BMxBN tile, BK=64, 4 waves (2x2 grid).
template <int BM, int BN, bool OUT_BF16>
__global__ __launch_bounds__(256) void mgemm_k(const u16* __restrict__ A,
                                               const u16* __restrict__ B,
                                               void* __restrict__ C, int K,
                                               int lda, int ldb, int ldc) {
  constexpr int BK = 64;
  constexpr int FM = BM / 32, FN = BN / 32;
  __shared__ u16 As[2][BM * BK];
  __shared__ u16 Bs[2][BN * BK];
  const int t = threadIdx.x;
  const int lane = t & 63, wave = t >> 6;
  const int l15 = lane & 15, l4 = lane >> 4;
  const int row0 = blockIdx.y * BM, col0 = blockIdx.x * BN;
  const int wr = (wave >> 1) * (BM / 2), wc = (wave & 1) * (BN / 2);
  const int srow = t >> 3;               // staging row within a 32-row pass
  const int sch = (t & 7) ^ (srow & 7);  // swizzled source chunk
  f32x4 acc[FM][FN] = {};

  auto STG = [&](int buf, int k0) {
#pragma unroll
    for (int p = 0; p < BM / 32; ++p)
      gload16(&A[(long)(row0 + p * 32 + srow) * lda + k0 + sch * 8],
              &As[buf][(p * 256 + wave * 64) * 8]);
#pragma unroll
    for (int p = 0; p < BN / 32; ++p)
      gload16(&B[(long)(col0 + p * 32 + srow) * ldb + k0 + sch * 8],
              &Bs[buf][(p * 256 + wave * 64) * 8]);
  };
  auto COMP = [&](int buf) {
#pragma unroll
    for (int kk = 0; kk < BK / 32; ++kk) {
      s16x8 a[FM], bfr[FN];
#pragma unroll
      for (int i = 0; i < FM; i++) {
        int r = wr + i * 16 + l15;
        int ph = (kk * 4 + l4) ^ (r & 7);
        a[i] = *(const s16x8*)&As[buf][r * 64 + ph * 8];
      }
#pragma unroll
      for (int j = 0; j < FN; j++) {
        int r = wc + j * 16 + l15;
        int ph = (kk * 4 + l4) ^ (r & 7);
        bfr[j] = *(const s16x8*)&Bs[buf][r * 64 + ph * 8];
      }
#pragma unroll
      for (int i = 0; i < FM; i++)
#pragma unroll
        for (int j = 0; j < FN; j++)
          acc[i][j] = mfma_bf16(a[i], bfr[j], acc[i][j]);
    }
  };

  STG(0, 0);
  __syncthreads();          // drains vmcnt(0): buf0 ready
  int cur = 0;
  for (int k0 = BK; k0 < K; k0 += BK) {
    STG(cur ^ 1, k0);       // issue next tile while computing current
    COMP(cur);
    __syncthreads();        // one barrier per iter (drains staging)
    cur ^= 1;
  }
  COMP(cur);

#pragma unroll
  for (int i = 0; i < FM; i++)
#pragma unroll
    for (int j = 0; j < FN; j++)
#pragma unroll
      for (int q = 0; q < 4; q++) {
        long r = row0 + wr + i * 16 + l4 * 4 + q;
        long c = col0 + wc + j * 16 + l15;
        if constexpr (OUT_BF16)
          ((u16*)C)[r * ldc + c] = f2b(acc[i][j][q]);
        else
          ((float*)C)[r * ldc + c] = acc[i][j][q];
      }
}

// ---------------- fused attention: norm + QK^T + softmax + PV ---------------
// grid 512: blk -> bh = blk&127, quarter = blk>>7. 4 waves x 16 q-rows.
__global__ __launch_bounds__(256) void attn_k(const u16* __restrict__ qkv,
                                              const float* __restrict__ temp,
                                              u16* __restrict__ attN) {
  int blk = blockIdx.x;
  int bh = blk & 127, quar = blk >> 7;
  int b = bh >> 3, h = bh & 7;
  __shared__ u16 qs[64][40];    // this quarter's q rows, l2-normed * temp
  __shared__ u16 ks[256][40];   // all keys, l2-normed
  __shared__ u16 vs[32][264];   // V^T [d][m]
  __shared__ u16 Ps[4][16][40]; // per-wave P chunk transpose buffer
  int t = threadIdx.x, lane = t & 63, wave = t >> 6;
  int l15 = lane & 15, l4 = lane >> 4;
  long base = (long)b * 256;

  {  // stage V^T rows (contiguous in qkv)
    const u16* V = qkv + (long)(512 + h * 32) * 4096 + base;
#pragma unroll
    for (int p = 0; p < 4; ++p) {
      int c = p * 256 + t;
      int row = c >> 5, off = (c & 31) * 8;
      *(u16x8*)&vs[row][off] = *(const u16x8*)&V[(long)row * 4096 + off];
    }
  }
  {  // stage K with l2norm: thread t owns key l=t
    const u16* Kp = qkv + (long)(256 + h * 32) * 4096 + base + t;
    float v[32], ss = 0.f;
#pragma unroll
    for (int d = 0; d < 32; ++d) {
      v[d] = b2f(Kp[(long)d * 4096]);
      ss += v[d] * v[d];
    }
    float sc = 1.f / fmaxf(sqrtf(ss), 1e-12f);
#pragma unroll
    for (int d = 0; d < 32; ++d) ks[t][d] = f2b(v[d] * sc);
  }
  if (t < 64) {  // stage this quarter's Q with l2norm * temperature
    const u16* Qp = qkv + (long)(h * 32) * 4096 + base + quar * 64 + t;
    float v[32], ss = 0.f;
#pragma unroll
    for (int d = 0; d < 32; ++d) {
      v[d] = b2f(Qp[(long)d * 4096]);
      ss += v[d] * v[d];
    }
    float sc = temp[h] / fmaxf(sqrtf(ss), 1e-12f);
#pragma unroll
    for (int d = 0; d < 32; ++d) qs[t][d] = f2b(v[d] * sc);
  }
  __syncthreads();

  int r0 = wave * 16;
  s16x8 aq = *(const s16x8*)&qs[r0 + l15][l4 * 8];
  f32x4 O[2] = {};
  float mrow[4], lrow[4];
#pragma unroll
  for (int q = 0; q < 4; ++q) {
    mrow[q] = -1e30f;
    lrow[q] = 0.f;
  }

  for (int m0 = 0; m0 < 256; m0 += 32) {
    f32x4 s[2] = {};
    s16x8 bk_[2];
#pragma unroll
    for (int j = 0; j < 2; ++j)
      bk_[j] = *(const s16x8*)&ks[m0 + j * 16 + l15][l4 * 8];
#pragma unroll
    for (int j = 0; j < 2; ++j) s[j] = mfma_bf16(aq, bk_[j], s[j]);
    float cm[4];
#pragma unroll
    for (int q = 0; q < 4; ++q) cm[q] = fmaxf(s[0][q], s[1][q]);
#pragma unroll
    for (int sh = 1; sh < 16; sh <<= 1)
#pragma unroll
      for (int q = 0; q < 4; ++q) cm[q] = fmaxf(cm[q], __shfl_xor(cm[q], sh));
    float al[4], ps[4];
#pragma unroll
    for (int q = 0; q < 4; ++q) {
      float mn = fmaxf(mrow[q], cm[q]);
      al[q] = __expf(mrow[q] - mn);
      mrow[q] = mn;
      float p0 = __expf(s[0][q] - mn);
      float p1 = __expf(s[1][q] - mn);
      s[0][q] = p0;
      s[1][q] = p1;
      ps[q] = p0 + p1;
    }
#pragma unroll
    for (int sh = 1; sh < 16; sh <<= 1)
#pragma unroll
      for (int q = 0; q < 4; ++q) ps[q] += __shfl_xor(ps[q], sh);
#pragma unroll
    for (int q = 0; q < 4; ++q) lrow[q] = lrow[q] * al[q] + ps[q];
#pragma unroll
    for (int jd = 0; jd < 2; ++jd)
#pragma unroll
      for (int q = 0; q < 4; ++q) O[jd][q] *= al[q];
#pragma unroll
    for (int j = 0; j < 2; ++j)
#pragma unroll
      for (int q = 0; q < 4; ++q)
        Ps[wave][l4 * 4 + q][j * 16 + l15] = f2b(s[j][q]);
    s16x8 pa = *(const s16x8*)&Ps[wave][l15][l4 * 8];
    s16x8 bv[2];
#pragma unroll
    for (int jd = 0; jd < 2; ++jd)
      bv[jd] = *(const s16x8*)&vs[jd * 16 + l15][m0 + l4 * 8];
#pragma unroll
    for (int jd = 0; jd < 2; ++jd) O[jd] = mfma_bf16(pa, bv[jd], O[jd]);
  }
  long rbase = base + quar * 64 + r0;
#pragma unroll
  for (int jd = 0; jd < 2; ++jd)
#pragma unroll
    for (int q = 0; q < 4; ++q)
      attN[(rbase + l4 * 4 + q) * 256 + h * 32 + jd * 16 + l15] =
          f2b(O[jd][q] / lrow[q]);
}

// ---------------- analytic BN stats, preload-all, bf16 lowT -----------------
__global__ __launch_bounds__(256) void stats_k(const u16* __restrict__ low,
                                               const float* __restrict__ gamma,
                                               const float* __restrict__ beta,
                                               float* __restrict__ kA,
                                               float* __restrict__ kB) {
  int o = blockIdx.x, t = threadIdx.x;
  __shared__ float Lall[16][256];
  __shared__ float cw[16];
  __shared__ float A3[16][3];
  __shared__ float r1[4], r2[4];

  {  // load lowB[o][...] (8 KB bf16) -> f32 LDS
    const u16* Lp = low + (long)o * 4096;
#pragma unroll
    for (int q = 0; q < 2; ++q) {
      int idx = (q * 256 + t) * 8;     // pixel-linear 0..4095, 8-aligned
      u16x8 v = *(const u16x8*)&Lp[idx];
      int b = idx >> 8, pix = idx & 255;
#pragma unroll
      for (int e = 0; e < 8; ++e) Lall[b][pix + e] = b2f(v[e]);
    }
  }
  if (t < 16) {
    cw[t] = 0.f;
    A3[t][0] = A3[t][1] = A3[t][2] = 0.f;
  }
  __syncthreads();
  if (t < 64) {
    float src = 0.25f * t - 0.375f;
    float fl = floorf(src);
    float f = src - fl;
    int i0 = (int)fl, i1 = i0 + 1;
    i0 = max(0, min(15, i0));
    i1 = max(0, min(15, i1));
    float w0 = 1.f - f, w1 = f;
    atomicAdd(&cw[i0], w0);
    atomicAdd(&cw[i1], w1);
    if (i0 == i1)
      atomicAdd(&A3[i0][1], 1.f);
    else {
      atomicAdd(&A3[i0][1], w0 * w0);
      atomicAdd(&A3[i1][1], w1 * w1);
      atomicAdd(&A3[i0][2], w0 * w1);
      atomicAdd(&A3[i1][0], w0 * w1);
    }
  }
  __syncthreads();
  int i = t >> 4, j = t & 15;
  float s1 = 0.f, s2 = 0.f;
#pragma unroll 4
  for (int b = 0; b < 16; ++b) {
    float Lc = Lall[b][t];
    s1 += cw[i] * cw[j] * Lc;
    float a2 = 0.f;
#pragma unroll
    for (int di = -1; di <= 1; ++di) {
      int ii = max(0, min(15, i + di));
      float ay = A3[i][di + 1];
#pragma unroll
      for (int dj = -1; dj <= 1; ++dj) {
        int jj = max(0, min(15, j + dj));
        a2 += ay * A3[j][dj + 1] * Lall[b][ii * 16 + jj];
      }
    }
    s2 += a2 * Lc;
  }
  int lane = t & 63, wid = t >> 6;
  for (int off = 32; off; off >>= 1) {
    s1 += __shfl_down(s1, off);
    s2 += __shfl_down(s2, off);
  }
  if (lane == 0) {
    r1[wid] = s1;
    r2[wid] = s2;
  }
  __syncthreads();
  if (t == 0) {
    s1 = r1[0] + r1[1] + r1[2] + r1[3];
    s2 = r2[0] + r2[1] + r2[2] + r2[3];
    float mean = s1 * (1.f / 65536.f);
    float var = s2 * (1.f / 65536.f) - mean * mean;
    float is = rsqrtf(var + 1e-5f);
    float g = gamma[o];
    kA[o] = g * is;
    kB[o] = beta[o] - mean * g * is;
  }
}

// ---------------- fused bilinear 4x upsample + BN affine (bf16 lowT) --------
__global__ __launch_bounds__(256) void up_bn_k(const u16* __restrict__ low,
                                               const float* __restrict__ kA,
                                               const float* __restrict__ kB,
                                               float* __restrict__ out) {
  long bo = blockIdx.x;               // b*1024 + o
  int b = (int)(bo >> 10), o = (int)(bo & 1023);
  int t = threadIdx.x;
  __shared__ float Ls[256];
  Ls[t] = b2f(low[(long)o * 4096 + b * 256 + t]);
  __syncthreads();
  float a = kA[o], bb = kB[o];
  float* op = out + bo * 4096;
#pragma unroll
  for (int it = 0; it < 4; ++it) {
    int idx = it * 1024 + t * 4;
    int y = idx >> 6, x0 = idx & 63;
    float sy = 0.25f * y - 0.375f;
    float fly = floorf(sy);
    float fy = sy - fly;
    int y0 = max(0, min(15, (int)fly));
    int y1 = max(0, min(15, (int)fly + 1));
    const float* R0 = &Ls[y0 * 16];
    const float* R1 = &Ls[y1 * 16];
    float vout[4];
#pragma unroll
    for (int jj = 0; jj < 4; ++jj) {
      int xx = x0 + jj;
      float sx = 0.25f * xx - 0.375f;
      float flx = floorf(sx);
      float fx = sx - flx;
      int x0i = max(0, min(15, (int)flx));
      int x1i = max(0, min(15, (int)flx + 1));
      float v0 = R0[x0i] + fx * (R0[x1i] - R0[x0i]);
      float v1 = R1[x0i] + fx * (R1[x1i] - R1[x0i]);
      vout[jj] = a * (v0 + fy * (v1 - v0)) + bb;
    }
    float4 r;
    r.x = vout[0]; r.y = vout[1]; r.z = vout[2]; r.w = vout[3];
    *(float4*)(op + idx) = r;
  }
}

// ---------------------------------------------------------------------------
extern "C" void kernel_launch(void* const* d_in, const int* in_sizes, int n_in,
                              void* d_out, int out_size, void* d_ws,
                              size_t ws_size, hipStream_t stream) {
  const float* x = (const float*)d_in[0];
  const float* w_qkv = (const float*)d_in[1];
  const float* temp = (const float*)d_in[2];
  const float* w_proj = (const float*)d_in[3];
  const float* gamma = (const float*)d_in[4];
  const float* beta = (const float*)d_in[5];
  float* out = (float*)d_out;
  char* w = (char*)d_ws;

  u16* wqkv_b = (u16*)(w);                 // 1.50 MB
  u16* wproj_b = (u16*)(w + 1572864);      // 0.50 MB
  u16* xrN = (u16*)(w + 2097152);          // 8.0 MB  [4096][1024]
  u16* qkvb = (u16*)(w + 10485760);        // 6.0 MB  [768][4096]
  u16* attN = (u16*)(w + 16777216);        // 2.0 MB  [4096][256]
  u16* lowB = (u16*)(w + 18874368);        // 8.0 MB  [1024][4096] bf16
  float* kA = (float*)(w + 27262976);
  float* kB = (float*)(w + 27267072);

  // 1) weights->bf16 + pool in one launch
  cvtpool_k<<<17408, 256, 0, stream>>>(w_qkv, wqkv_b, 196608, w_proj, wproj_b,
                                       65536, x, xrN);
  // 2) qkv GEMM: M=768,N=4096,K=1024
  mgemm_k<128, 64, true><<<dim3(64, 6), 256, 0, stream>>>(
      wqkv_b, xrN, qkvb, 1024, 1024, 1024, 4096);
  // 3) fused attention -> attN (512 blocks: bh x quarter)
  attn_k<<<512, 256, 0, stream>>>(qkvb, temp, attN);
  // 4) proj GEMM at low res: M=1024,N=4096,K=256 -> lowB bf16
  mgemm_k<128, 64, true><<<dim3(64, 8), 256, 0, stream>>>(
      wproj_b, attN, lowB, 256, 256, 256, 4096);
  // 5) analytic BN stats (bf16 lowT)
  stats_k<<<1024, 256, 0, stream>>>(lowB, gamma, beta, kA, kB);
  // 6) fused upsample + BN -> out
  up_bn_k<<<16384, 256, 0, stream>>>(lowB, kA, kB, out);
}

// Round 10
// 157.287 us; speedup vs baseline: 1.3742x; 1.0489x over previous
//
#include <hip/hip_runtime.h>
#include <math.h>

// ---------------------------------------------------------------------------
// HMHA round 10: R9 + ONE change — pool rewritten as LDS-tiled transpose-pool.
//   Old pool: block (b,c) wrote 256 x 2B at 2KB stride -> up to 32x write
//   amplification (partial-line RFO). New: block (b, pix-row i, 32-ch group)
//   stages 32 KB via coalesced 1KB-per-wave reads, pools in LDS (identical
//   summation order), writes full 64B line segments exactly once.
// ---------------------------------------------------------------------------

typedef unsigned short u16;
typedef u16 u16x8 __attribute__((ext_vector_type(8)));
typedef u16 u16x4 __attribute__((ext_vector_type(4)));
typedef short s16x8 __attribute__((ext_vector_type(8)));
typedef float f32x4 __attribute__((ext_vector_type(4)));

__device__ __forceinline__ float b2f(u16 u) {
  union { unsigned u; float f; } v;
  v.u = (unsigned)u << 16;
  return v.f;
}
__device__ __forceinline__ u16 f2b(float f) {
  union { float f; unsigned u; } v;
  v.f = f;
  unsigned r = (v.u + 0x7fffu + ((v.u >> 16) & 1u)) >> 16;
  return (u16)r;
}
__device__ __forceinline__ f32x4 mfma_bf16(s16x8 a, s16x8 b, f32x4 c) {
  return __builtin_amdgcn_mfma_f32_16x16x32_bf16(a, b, c, 0, 0, 0);
}
// global -> LDS direct 16B load (dest = wave-uniform base + lane*16)
__device__ __forceinline__ void gload16(const u16* g, u16* l) {
  unsigned loff = (unsigned)(unsigned long long)l;
  __builtin_amdgcn_global_load_lds(
      (const __attribute__((address_space(1))) void*)g,
      (__attribute__((address_space(3))) void*)loff, 16, 0, 0);
}

// ---------------- fused: weight cvt (blocks 0..1023) + pool (rest) ----------
// pool blocks: bid2 in [0,8192): b=bid2>>9, i=(bid2>>5)&15, cg=bid2&31.
// Stage x[b][cg*32..+32][rows 4i..4i+3][all w] (32 x 1KB contiguous) to LDS,
// pool 4x4 windows, write xrN[b*256+i*16+j][cg*32..+32] (64B full lines).
__global__ __launch_bounds__(256) void cvtpool_k(
    const float* __restrict__ wa, u16* __restrict__ da, int n4a,
    const float* __restrict__ wb, u16* __restrict__ db, int n4b,
    const float* __restrict__ x, u16* __restrict__ xrN) {
  int bid = blockIdx.x;
  if (bid < 1024) {
    int idx = bid * 256 + threadIdx.x;
    const float* s;
    u16* d;
    if (idx < n4a) {
      s = wa; d = da;
    } else {
      idx -= n4a;
      if (idx >= n4b) return;
      s = wb; d = db;
    }
    float4 v = ((const float4*)s)[idx];
    u16x4 o;
    o.x = f2b(v.x); o.y = f2b(v.y); o.z = f2b(v.z); o.w = f2b(v.w);
    ((u16x4*)d)[idx] = o;
    return;
  }
  bid -= 1024;
  int b = bid >> 9, i = (bid >> 5) & 15, cg = bid & 31;
  __shared__ float Ls[32][260];       // 260: 16B-aligned rows, b128-friendly
  int t = threadIdx.x, lane = t & 63, wave = t >> 6;
  const float* xb = x + ((long)(b * 1024 + cg * 32)) * 4096 + i * 256;
#pragma unroll
  for (int it = 0; it < 8; ++it) {
    int cl = it * 4 + wave;           // channel-local 0..31; wave reads 1KB
    float4 v = *(const float4*)(xb + (long)cl * 4096 + lane * 4);
    *(float4*)&Ls[cl][lane * 4] = v;
  }
  __syncthreads();
  int c = t & 31, jr = (t >> 5) & 7;
#pragma unroll
  for (int q = 0; q < 2; ++q) {
    int j = jr + q * 8;
    float s = 0.f;
#pragma unroll
    for (int r = 0; r < 4; ++r) {
      float4 v = *(const float4*)&Ls[c][r * 64 + j * 4];
      s += ((v.x + v.y) + v.z) + v.w;   // same association as old pool
    }
    xrN[((long)(b * 256 + i * 16 + j)) * 1024 + cg * 32 + c] =
        f2b(s * 0.0625f);
  }
}

// ---------------- MFMA GEMM, double-buffered, gload_lds + XOR swizzle -------
// C[M][N] = A[M][K] * B[N][K]^T. BMxBN tile, BK=64, 4 waves (2x2 grid).
template <int BM, int BN, bool OUT_BF16>
__global__ __launch_bounds__(256) void mgemm_k(const u16* __restrict__ A,
                                               const u16* __restrict__ B,
                                               void* __restrict__ C, int K,
                                               int lda, int ldb, int ldc) {
  constexpr int BK = 64;
  constexpr int FM = BM / 32, FN = BN / 32;
  __shared__ u16 As[2][BM * BK];
  __shared__ u16 Bs[2][BN * BK];
  const int t = threadIdx.x;
  const int lane = t & 63, wave = t >> 6;
  const int l15 = lane & 15, l4 = lane >> 4;
  const int row0 = blockIdx.y * BM, col0 = blockIdx.x * BN;
  const int wr = (wave >> 1) * (BM / 2), wc = (wave & 1) * (BN / 2);
  const int srow = t >> 3;               // staging row within a 32-row pass
  const int sch = (t & 7) ^ (srow & 7);  // swizzled source chunk
  f32x4 acc[FM][FN] = {};

  auto STG = [&](int buf, int k0) {
#pragma unroll
    for (int p = 0; p < BM / 32; ++p)
      gload16(&A[(long)(row0 + p * 32 + srow) * lda + k0 + sch * 8],
              &As[buf][(p * 256 + wave * 64) * 8]);
#pragma unroll
    for (int p = 0; p < BN / 32; ++p)
      gload16(&B[(long)(col0 + p * 32 + srow) * ldb + k0 + sch * 8],
              &Bs[buf][(p * 256 + wave * 64) * 8]);
  };
  auto COMP = [&](int buf) {
#pragma unroll
    for (int kk = 0; kk < BK / 32; ++kk) {
      s16x8 a[FM], bfr[FN];
#pragma unroll
      for (int i = 0; i < FM; i++) {
        int r = wr + i * 16 + l15;
        int ph = (kk * 4 + l4) ^ (r & 7);
        a[i] = *(const s16x8*)&As[buf][r * 64 + ph * 8];
      }
#pragma unroll
      for (int j = 0; j < FN; j++) {
        int r = wc + j * 16 + l15;
        int ph = (kk * 4 + l4) ^ (r & 7);
        bfr[j] = *(const s16x8*)&Bs[buf][r * 64 + ph * 8];
      }
#pragma unroll
      for (int i = 0; i < FM; i++)
#pragma unroll
        for (int j = 0; j < FN; j++)
          acc[i][j] = mfma_bf16(a[i], bfr[j], acc[i][j]);
    }
  };

  STG(0, 0);
  __syncthreads();          // drains vmcnt(0): buf0 ready
  int cur = 0;
  for (int k0 = BK; k0 < K; k0 += BK) {
    STG(cur ^ 1, k0);       // issue next tile while computing current
    COMP(cur);
    __syncthreads();        // one barrier per iter (drains staging)
    cur ^= 1;
  }
  COMP(cur);

#pragma unroll
  for (int i = 0; i < FM; i++)
#pragma unroll
    for (int j = 0; j < FN; j++)
#pragma unroll
      for (int q = 0; q < 4; q++) {
        long r = row0 + wr + i * 16 + l4 * 4 + q;
        long c = col0 + wc + j * 16 + l15;
        if constexpr (OUT_BF16)
          ((u16*)C)[r * ldc + c] = f2b(acc[i][j][q]);
        else
          ((float*)C)[r * ldc + c] = acc[i][j][q];
      }
}

// ---------------- fused attention: norm + QK^T + softmax + PV ---------------
// grid 512: blk -> bh = blk&127, quarter = blk>>7. 4 waves x 16 q-rows.
__global__ __launch_bounds__(256) void attn_k(const u16* __restrict__ qkv,
                                              const float* __restrict__ temp,
                                              u16* __restrict__ attN) {
  int blk = blockIdx.x;
  int bh = blk & 127, quar = blk >> 7;
  int b = bh >> 3, h = bh & 7;
  __shared__ u16 qs[64][40];    // this quarter's q rows, l2-normed * temp
  __shared__ u16 ks[256][40];   // all keys, l2-normed
  __shared__ u16 vs[32][264];   // V^T [d][m]
  __shared__ u16 Ps[4][16][40]; // per-wave P chunk transpose buffer
  int t = threadIdx.x, lane = t & 63, wave = t >> 6;
  int l15 = lane & 15, l4 = lane >> 4;
  long base = (long)b * 256;

  {  // stage V^T rows (contiguous in qkv)
    const u16* V = qkv + (long)(512 + h * 32) * 4096 + base;
#pragma unroll
    for (int p = 0; p < 4; ++p) {
      int c = p * 256 + t;
      int row = c >> 5, off = (c & 31) * 8;
      *(u16x8*)&vs[row][off] = *(const u16x8*)&V[(long)row * 4096 + off];
    }
  }
  {  // stage K with l2norm: thread t owns key l=t
    const u16* Kp = qkv + (long)(256 + h * 32) * 4096 + base + t;
    float v[32], ss = 0.f;
#pragma unroll
    for (int d = 0; d < 32; ++d) {
      v[d] = b2f(Kp[(long)d * 4096]);
      ss += v[d] * v[d];
    }
    float sc = 1.f / fmaxf(sqrtf(ss), 1e-12f);
#pragma unroll
    for (int d = 0; d < 32; ++d) ks[t][d] = f2b(v[d] * sc);
  }
  if (t < 64) {  // stage this quarter's Q with l2norm * temperature
    const u16* Qp = qkv + (long)(h * 32) * 4096 + base + quar * 64 + t;
    float v[32], ss = 0.f;
#pragma unroll
    for (int d = 0; d < 32; ++d) {
      v[d] = b2f(Qp[(long)d * 4096]);
      ss += v[d] * v[d];
    }
    float sc = temp[h] / fmaxf(sqrtf(ss), 1e-12f);
#pragma unroll
    for (int d = 0; d < 32; ++d) qs[t][d] = f2b(v[d] * sc);
  }
  __syncthreads();

  int r0 = wave * 16;
  s16x8 aq = *(const s16x8*)&qs[r0 + l15][l4 * 8];
  f32x4 O[2] = {};
  float mrow[4], lrow[4];
#pragma unroll
  for (int q = 0; q < 4; ++q) {
    mrow[q] = -1e30f;
    lrow[q] = 0.f;
  }

  for (int m0 = 0; m0 < 256; m0 += 32) {
    f32x4 s[2] = {};
    s16x8 bk_[2];
#pragma unroll
    for (int j = 0; j < 2; ++j)
      bk_[j] = *(const s16x8*)&ks[m0 + j * 16 + l15][l4 * 8];
#pragma unroll
    for (int j = 0; j < 2; ++j) s[j] = mfma_bf16(aq, bk_[j], s[j]);
    float cm[4];
#pragma unroll
    for (int q = 0; q < 4; ++q) cm[q] = fmaxf(s[0][q], s[1][q]);
#pragma unroll
    for (int sh = 1; sh < 16; sh <<= 1)
#pragma unroll
      for (int q = 0; q < 4; ++q) cm[q] = fmaxf(cm[q], __shfl_xor(cm[q], sh));
    float al[4], ps[4];
#pragma unroll
    for (int q = 0; q < 4; ++q) {
      float mn = fmaxf(mrow[q], cm[q]);
      al[q] = __expf(mrow[q] - mn);
      mrow[q] = mn;
      float p0 = __expf(s[0][q] - mn);
      float p1 = __expf(s[1][q] - mn);
      s[0][q] = p0;
      s[1][q] = p1;
      ps[q] = p0 + p1;
    }
#pragma unroll
    for (int sh = 1; sh < 16; sh <<= 1)
#pragma unroll
      for (int q = 0; q < 4; ++q) ps[q] += __shfl_xor(ps[q], sh);
#pragma unroll
    for (int q = 0; q < 4; ++q) lrow[q] = lrow[q] * al[q] + ps[q];
#pragma unroll
    for (int jd = 0; jd < 2; ++jd)
#pragma unroll
      for (int q = 0; q < 4; ++q) O[jd][q] *= al[q];
#pragma unroll
    for (int j = 0; j < 2; ++j)
#pragma unroll
      for (int q = 0; q < 4; ++q)
        Ps[wave][l4 * 4 + q][j * 16 + l15] = f2b(s[j][q]);
    s16x8 pa = *(const s16x8*)&Ps[wave][l15][l4 * 8];
    s16x8 bv[2];
#pragma unroll
    for (int jd = 0; jd < 2; ++jd)
      bv[jd] = *(const s16x8*)&vs[jd * 16 + l15][m0 + l4 * 8];
#pragma unroll
    for (int jd = 0; jd < 2; ++jd) O[jd] = mfma_bf16(pa, bv[jd], O[jd]);
  }
  long rbase = base + quar * 64 + r0;
#pragma unroll
  for (int jd = 0; jd < 2; ++jd)
#pragma unroll
    for (int q = 0; q < 4; ++q)
      attN[(rbase + l4 * 4 + q) * 256 + h * 32 + jd * 16 + l15] =
          f2b(O[jd][q] / lrow[q]);
}

// ---------------- analytic BN stats, preload-all, bf16 lowT -----------------
__global__ __launch_bounds__(256) void stats_k(const u16* __restrict__ low,
                                               const float* __restrict__ gamma,
                                               const float* __restrict__ beta,
                                               float* __restrict__ kA,
                                               float* __restrict__ kB) {
  int o = blockIdx.x, t = threadIdx.x;
  __shared__ float Lall[16][256];
  __shared__ float cw[16];
  __shared__ float A3[16][3];
  __shared__ float r1[4], r2[4];

  {  // load lowB[o][...] (8 KB bf16) -> f32 LDS
    const u16* Lp = low + (long)o * 4096;
#pragma unroll
    for (int q = 0; q < 2; ++q) {
      int idx = (q * 256 + t) * 8;     // pixel-linear 0..4095, 8-aligned
      u16x8 v = *(const u16x8*)&Lp[idx];
      int b = idx >> 8, pix = idx & 255;
#pragma unroll
      for (int e = 0; e < 8; ++e) Lall[b][pix + e] = b2f(v[e]);
    }
  }
  if (t < 16) {
    cw[t] = 0.f;
    A3[t][0] = A3[t][1] = A3[t][2] = 0.f;
  }
  __syncthreads();
  if (t < 64) {
    float src = 0.25f * t - 0.375f;
    float fl = floorf(src);
    float f = src - fl;
    int i0 = (int)fl, i1 = i0 + 1;
    i0 = max(0, min(15, i0));
    i1 = max(0, min(15, i1));
    float w0 = 1.f - f, w1 = f;
    atomicAdd(&cw[i0], w0);
    atomicAdd(&cw[i1], w1);
    if (i0 == i1)
      atomicAdd(&A3[i0][1], 1.f);
    else {
      atomicAdd(&A3[i0][1], w0 * w0);
      atomicAdd(&A3[i1][1], w1 * w1);
      atomicAdd(&A3[i0][2], w0 * w1);
      atomicAdd(&A3[i1][0], w0 * w1);
    }
  }
  __syncthreads();
  int i = t >> 4, j = t & 15;
  float s1 = 0.f, s2 = 0.f;
#pragma unroll 4
  for (int b = 0; b < 16; ++b) {
    float Lc = Lall[b][t];
    s1 += cw[i] * cw[j] * Lc;
    float a2 = 0.f;
#pragma unroll
    for (int di = -1; di <= 1; ++di) {
      int ii = max(0, min(15, i + di));
      float ay = A3[i][di + 1];
#pragma unroll
      for (int dj = -1; dj <= 1; ++dj) {
        int jj = max(0, min(15, j + dj));
        a2 += ay * A3[j][dj + 1] * Lall[b][ii * 16 + jj];
      }
    }
    s2 += a2 * Lc;
  }
  int lane = t & 63, wid = t >> 6;
  for (int off = 32; off; off >>= 1) {
    s1 += __shfl_down(s1, off);
    s2 += __shfl_down(s2, off);
  }
  if (lane == 0) {
    r1[wid] = s1;
    r2[wid] = s2;
  }
  __syncthreads();
  if (t == 0) {
    s1 = r1[0] + r1[1] + r1[2] + r1[3];
    s2 = r2[0] + r2[1] + r2[2] + r2[3];
    float mean = s1 * (1.f / 65536.f);
    float var = s2 * (1.f / 65536.f) - mean * mean;
    float is = rsqrtf(var + 1e-5f);
    float g = gamma[o];
    kA[o] = g * is;
    kB[o] = beta[o] - mean * g * is;
  }
}

// ---------------- fused bilinear 4x upsample + BN affine (bf16 lowT) --------
__global__ __launch_bounds__(256) void up_bn_k(const u16* __restrict__ low,
                                               const float* __restrict__ kA,
                                               const float* __restrict__ kB,
                                               float* __restrict__ out) {
  long bo = blockIdx.x;               // b*1024 + o
  int b = (int)(bo >> 10), o = (int)(bo & 1023);
  int t = threadIdx.x;
  __shared__ float Ls[256];
  Ls[t] = b2f(low[(long)o * 4096 + b * 256 + t]);
  __syncthreads();
  float a = kA[o], bb = kB[o];
  float* op = out + bo * 4096;
#pragma unroll
  for (int it = 0; it < 4; ++it) {
    int idx = it * 1024 + t * 4;
    int y = idx >> 6, x0 = idx & 63;
    float sy = 0.25f * y - 0.375f;
    float fly = floorf(sy);
    float fy = sy - fly;
    int y0 = max(0, min(15, (int)fly));
    int y1 = max(0, min(15, (int)fly + 1));
    const float* R0 = &Ls[y0 * 16];
    const float* R1 = &Ls[y1 * 16];
    float vout[4];
#pragma unroll
    for (int jj = 0; jj < 4; ++jj) {
      int xx = x0 + jj;
      float sx = 0.25f * xx - 0.375f;
      float flx = floorf(sx);
      float fx = sx - flx;
      int x0i = max(0, min(15, (int)flx));
      int x1i = max(0, min(15, (int)flx + 1));
      float v0 = R0[x0i] + fx * (R0[x1i] - R0[x0i]);
      float v1 = R1[x0i] + fx * (R1[x1i] - R1[x0i]);
      vout[jj] = a * (v0 + fy * (v1 - v0)) + bb;
    }
    float4 r;
    r.x = vout[0]; r.y = vout[1]; r.z = vout[2]; r.w = vout[3];
    *(float4*)(op + idx) = r;
  }
}

// ---------------------------------------------------------------------------
extern "C" void kernel_launch(void* const* d_in, const int* in_sizes, int n_in,
                              void* d_out, int out_size, void* d_ws,
                              size_t ws_size, hipStream_t stream) {
  const float* x = (const float*)d_in[0];
  const float* w_qkv = (const float*)d_in[1];
  const float* temp = (const float*)d_in[2];
  const float* w_proj = (const float*)d_in[3];
  const float* gamma = (const float*)d_in[4];
  const float* beta = (const float*)d_in[5];
  float* out = (float*)d_out;
  char* w = (char*)d_ws;

  u16* wqkv_b = (u16*)(w);                 // 1.50 MB
  u16* wproj_b = (u16*)(w + 1572864);      // 0.50 MB
  u16* xrN = (u16*)(w + 2097152);          // 8.0 MB  [4096][1024]
  u16* qkvb = (u16*)(w + 10485760);        // 6.0 MB  [768][4096]
  u16* attN = (u16*)(w + 16777216);        // 2.0 MB  [4096][256]
  u16* lowB = (u16*)(w + 18874368);        // 8.0 MB  [1024][4096] bf16
  float* kA = (float*)(w + 27262976);
  float* kB = (float*)(w + 27267072);

  // 1) weights->bf16 (1024 blocks) + LDS-tiled pool (8192 blocks)
  cvtpool_k<<<9216, 256, 0, stream>>>(w_qkv, wqkv_b, 196608, w_proj, wproj_b,
                                      65536, x, xrN);
  // 2) qkv GEMM: M=768,N=4096,K=1024
  mgemm_k<128, 64, true><<<dim3(64, 6), 256, 0, stream>>>(
      wqkv_b, xrN, qkvb, 1024, 1024, 1024, 4096);
  // 3) fused attention -> attN (512 blocks: bh x quarter)
  attn_k<<<512, 256, 0, stream>>>(qkvb, temp, attN);
  // 4) proj GEMM at low res: M=1024,N=4096,K=256 -> lowB bf16
  mgemm_k<128, 64, true><<<dim3(64, 8), 256, 0, stream>>>(
      wproj_b, attN, lowB, 256, 256, 256, 4096);
  // 5) analytic BN stats (bf16 lowT)
  stats_k<<<1024, 256, 0, stream>>>(lowB, gamma, beta, kA, kB);
  // 6) fused upsample + BN -> out
  up_bn_k<<<16384, 256, 0, stream>>>(lowB, kA, kB, out);
}